// Round 1
// baseline (388.178 us; speedup 1.0000x reference)
//
#include <hip/hip_runtime.h>
#include <hip/hip_bf16.h>

// Problem constants
#define BB 8
#define NN 512
#define AH 12
#define DIN 768
#define EE 64
#define MM (BB*NN)          // 4096
#define LEAKY 0.2f

#define TILE 64
#define BK 16

// ---------------------------------------------------------------------------
// GEMM 1: h[b][a][n][e] = feat[b][n][:] @ W[a][:][e]
// A: feat [4096][768] row-major. B: W [12][768][64] -> col = a*64+e, a fixed per block col-tile.
// ---------------------------------------------------------------------------
__global__ __launch_bounds__(256) void gemm_h_kernel(const float* __restrict__ A,
                                                     const float* __restrict__ W,
                                                     float* __restrict__ H) {
    __shared__ alignas(16) float As[BK][TILE + 4];
    __shared__ alignas(16) float Bs[BK][TILE + 4];
    int t = threadIdx.x;
    int a  = blockIdx.x;              // head (col tile == head, 64 cols)
    int m0 = blockIdx.y * TILE;
    int tx = t & 15, ty = t >> 4;
    float acc[4][4] = {};
    const float* Wa = W + a * (DIN * EE);
    int lrow = t >> 2, lk4 = (t & 3) << 2;   // A-tile load coords
    int bkk  = t >> 4, be4 = (t & 15) << 2;  // B-tile load coords

    for (int k0 = 0; k0 < DIN; k0 += BK) {
        float4 av = *(const float4*)&A[(m0 + lrow) * DIN + k0 + lk4];
        float4 bv = *(const float4*)&Wa[(k0 + bkk) * EE + be4];
        As[lk4 + 0][lrow] = av.x; As[lk4 + 1][lrow] = av.y;
        As[lk4 + 2][lrow] = av.z; As[lk4 + 3][lrow] = av.w;
        *(float4*)&Bs[bkk][be4] = bv;
        __syncthreads();
#pragma unroll
        for (int kk = 0; kk < BK; kk++) {
            float4 a4 = *(const float4*)&As[kk][ty << 2];
            float4 b4 = *(const float4*)&Bs[kk][tx << 2];
            acc[0][0] += a4.x * b4.x; acc[0][1] += a4.x * b4.y; acc[0][2] += a4.x * b4.z; acc[0][3] += a4.x * b4.w;
            acc[1][0] += a4.y * b4.x; acc[1][1] += a4.y * b4.y; acc[1][2] += a4.y * b4.z; acc[1][3] += a4.y * b4.w;
            acc[2][0] += a4.z * b4.x; acc[2][1] += a4.z * b4.y; acc[2][2] += a4.z * b4.z; acc[2][3] += a4.z * b4.w;
            acc[3][0] += a4.w * b4.x; acc[3][1] += a4.w * b4.y; acc[3][2] += a4.w * b4.z; acc[3][3] += a4.w * b4.w;
        }
        __syncthreads();
    }
#pragma unroll
    for (int i = 0; i < 4; i++) {
        int m = m0 + (ty << 2) + i;
        int b = m >> 9, n = m & 511;
        float4 o = { acc[i][0], acc[i][1], acc[i][2], acc[i][3] };
        *(float4*)&H[(((b * AH + a) << 9) + n) * EE + (tx << 2)] = o;
    }
}

// ---------------------------------------------------------------------------
// GEMM 2: gate[b][n][o] = sigmoid(feat[b][n][:] @ H_w[o][:] + H_b[o])
// B matrix is H_w transposed (B[d][o] = H_w[o][d]).
// ---------------------------------------------------------------------------
__global__ __launch_bounds__(256) void gemm_gate_kernel(const float* __restrict__ A,
                                                        const float* __restrict__ Hw,
                                                        const float* __restrict__ Hb,
                                                        float* __restrict__ G) {
    __shared__ alignas(16) float As[BK][TILE + 4];
    __shared__ alignas(16) float Bs[BK][TILE + 4];
    int t = threadIdx.x;
    int n0 = blockIdx.x * TILE;
    int m0 = blockIdx.y * TILE;
    int tx = t & 15, ty = t >> 4;
    float acc[4][4] = {};
    int lrow = t >> 2, lk4 = (t & 3) << 2;   // A-tile
    int bo   = t >> 2, bk4 = (t & 3) << 2;   // B-tile (from H_w rows)

    for (int k0 = 0; k0 < DIN; k0 += BK) {
        float4 av = *(const float4*)&A[(m0 + lrow) * DIN + k0 + lk4];
        float4 bv = *(const float4*)&Hw[(n0 + bo) * DIN + k0 + bk4];
        As[lk4 + 0][lrow] = av.x; As[lk4 + 1][lrow] = av.y;
        As[lk4 + 2][lrow] = av.z; As[lk4 + 3][lrow] = av.w;
        Bs[bk4 + 0][bo] = bv.x; Bs[bk4 + 1][bo] = bv.y;
        Bs[bk4 + 2][bo] = bv.z; Bs[bk4 + 3][bo] = bv.w;
        __syncthreads();
#pragma unroll
        for (int kk = 0; kk < BK; kk++) {
            float4 a4 = *(const float4*)&As[kk][ty << 2];
            float4 b4 = *(const float4*)&Bs[kk][tx << 2];
            acc[0][0] += a4.x * b4.x; acc[0][1] += a4.x * b4.y; acc[0][2] += a4.x * b4.z; acc[0][3] += a4.x * b4.w;
            acc[1][0] += a4.y * b4.x; acc[1][1] += a4.y * b4.y; acc[1][2] += a4.y * b4.z; acc[1][3] += a4.y * b4.w;
            acc[2][0] += a4.z * b4.x; acc[2][1] += a4.z * b4.y; acc[2][2] += a4.z * b4.z; acc[2][3] += a4.z * b4.w;
            acc[3][0] += a4.w * b4.x; acc[3][1] += a4.w * b4.y; acc[3][2] += a4.w * b4.z; acc[3][3] += a4.w * b4.w;
        }
        __syncthreads();
    }
    float4 hb = *(const float4*)&Hb[n0 + (tx << 2)];
#pragma unroll
    for (int i = 0; i < 4; i++) {
        int m = m0 + (ty << 2) + i;
        float4 o;
        float v;
        v = acc[i][0] + hb.x; o.x = 1.f / (1.f + expf(-v));
        v = acc[i][1] + hb.y; o.y = 1.f / (1.f + expf(-v));
        v = acc[i][2] + hb.z; o.z = 1.f / (1.f + expf(-v));
        v = acc[i][3] + hb.w; o.w = 1.f / (1.f + expf(-v));
        *(float4*)&G[m * DIN + n0 + (tx << 2)] = o;
    }
}

// ---------------------------------------------------------------------------
// src/dst: one wave per (b,a,n) row: src[R] = sum_e tanh(h[R][e]) * w_src[a][e]
// ---------------------------------------------------------------------------
__global__ __launch_bounds__(256) void src_dst_kernel(const float* __restrict__ H,
                                                      const float* __restrict__ wsrc,
                                                      const float* __restrict__ wdst,
                                                      float* __restrict__ srcb,
                                                      float* __restrict__ dstb) {
    int t = threadIdx.x;
    int wave = t >> 6, lane = t & 63;
    int R = (blockIdx.x << 2) + wave;        // row in [0, B*A*N)
    int a = (R >> 9) % AH;
    float th = tanhf(H[(R << 6) + lane]);
    float s = th * wsrc[(a << 6) + lane];
    float d = th * wdst[(a << 6) + lane];
#pragma unroll
    for (int off = 32; off >= 1; off >>= 1) {
        s += __shfl_down(s, off);
        d += __shfl_down(d, off);
    }
    if (lane == 0) { srcb[R] = s; dstb[R] = d; }
}

// ---------------------------------------------------------------------------
// Attention: block = (i-tile of 16 rows) x (b,a). Bitmask adjacency in LDS,
// two-pass softmax stats, PV with LDS-staged h tiles, fused elu+gate epilogue.
// ---------------------------------------------------------------------------
__global__ __launch_bounds__(256) void attn_kernel(const float* __restrict__ Hbuf,
                                                   const float* __restrict__ srcb,
                                                   const float* __restrict__ dstb,
                                                   const int* __restrict__ adj,
                                                   const float* __restrict__ bias,
                                                   const float* __restrict__ gate,
                                                   const float* __restrict__ feat,
                                                   float* __restrict__ out) {
    __shared__ float sdst[NN];
    __shared__ float ssrc[16];
    __shared__ unsigned smask[16][16];
    __shared__ float red[256];
    __shared__ float sm[16], sinvl[16];
    __shared__ int suni[16];
    __shared__ alignas(16) float h_s[128][64];
    __shared__ float p_s[16][132];

    int t = threadIdx.x;
    int y = blockIdx.y;                 // b*12 + a
    int i0 = blockIdx.x << 4;
    int bb = y / AH, a = y % AH;
    int ybase = y << 9;

    sdst[t]       = dstb[ybase + t];
    sdst[t + 256] = dstb[ybase + 256 + t];
    if (t < 16) ssrc[t] = srcb[ybase + i0 + t];

    // pack adjacency rows into bitmask (wave-wide ballot)
    const int* adjrow = adj + ((bb << 9) + i0) * NN;
#pragma unroll
    for (int it = 0; it < 32; it++) {
        int g = (it << 8) + t;
        int r = g >> 9, j = g & 511;
        int av = adjrow[(r << 9) + j];
        unsigned long long bal = __ballot(av != 0);
        if ((t & 63) == 0) {
            smask[r][j >> 5]       = (unsigned)bal;
            smask[r][(j >> 5) + 1] = (unsigned)(bal >> 32);
        }
    }
    __syncthreads();

    int r = t >> 4, sub = t & 15;
    float srcv = ssrc[r];

    // pass 1: row max over unmasked
    float lm = -1e30f;
    for (int jj = 0; jj < 32; jj++) {
        int j = sub + (jj << 4);
        if ((smask[r][j >> 5] >> (j & 31)) & 1) {
            float v = srcv + sdst[j];
            v = v >= 0.f ? v : LEAKY * v;
            lm = fmaxf(lm, v);
        }
    }
    red[t] = lm; __syncthreads();
    for (int off = 8; off; off >>= 1) {
        if (sub < off) red[t] = fmaxf(red[t], red[t + off]);
        __syncthreads();
    }
    float m_r = red[r << 4];
    __syncthreads();

    // pass 2: row sum of exp
    float ls = 0.f;
    for (int jj = 0; jj < 32; jj++) {
        int j = sub + (jj << 4);
        if ((smask[r][j >> 5] >> (j & 31)) & 1) {
            float v = srcv + sdst[j];
            v = v >= 0.f ? v : LEAKY * v;
            ls += expf(v - m_r);
        }
    }
    red[t] = ls; __syncthreads();
    for (int off = 8; off; off >>= 1) {
        if (sub < off) red[t] += red[t + off];
        __syncthreads();
    }
    if (sub == 0) {
        int uni = (m_r < -1e29f);        // no unmasked neighbors -> uniform 1/512
        suni[r] = uni;
        sm[r] = m_r;
        sinvl[r] = uni ? 0.f : 1.f / red[r << 4];
    }
    __syncthreads();

    // PV: thread = (row r, 4 cols e4..e4+3)
    float4 acc = {0.f, 0.f, 0.f, 0.f};
    int e4 = (t & 15) << 2;
    const float* hbase = Hbuf + ((long long)ybase << 6);

    for (int jt = 0; jt < 4; jt++) {
        int jb = jt << 7;
        // stage h tile [128][64]
#pragma unroll
        for (int q = 0; q < 8; q++) {
            int idx = (q << 8) + t;
            int jr = idx >> 4, ec = (idx & 15) << 2;
            *(float4*)&h_s[jr][ec] = *(const float4*)&hbase[((jb + jr) << 6) + ec];
        }
        // probability tile [16][128]
        {
            int js = (t & 15) << 3;
            float mm = sm[r]; float il = sinvl[r]; int uni = suni[r];
#pragma unroll
            for (int q = 0; q < 8; q++) {
                int jl = js + q, jg = jb + jl;
                float p;
                if (uni) p = (1.0f / 512.0f);
                else if ((smask[r][jg >> 5] >> (jg & 31)) & 1) {
                    float v = srcv + sdst[jg];
                    v = v >= 0.f ? v : LEAKY * v;
                    p = expf(v - mm) * il;
                } else p = 0.f;
                p_s[r][jl] = p;
            }
        }
        __syncthreads();
#pragma unroll 4
        for (int j = 0; j < 128; j++) {
            float4 hv = *(const float4*)&h_s[j][e4];
            float pv = p_s[r][j];
            acc.x += pv * hv.x; acc.y += pv * hv.y;
            acc.z += pv * hv.z; acc.w += pv * hv.w;
        }
        __syncthreads();
    }

    // epilogue: +bias, elu, gate blend
    int node = i0 + r;
    int base = ((bb << 9) + node) * DIN + (a << 6) + e4;
    float4 g4 = *(const float4*)&gate[base];
    float4 f4 = *(const float4*)&feat[base];
    float4 b4 = *(const float4*)&bias[e4];
    float4 o;
    float v;
    v = acc.x + b4.x; v = v > 0.f ? v : expm1f(v); o.x = g4.x * v + (1.f - g4.x) * f4.x;
    v = acc.y + b4.y; v = v > 0.f ? v : expm1f(v); o.y = g4.y * v + (1.f - g4.y) * f4.y;
    v = acc.z + b4.z; v = v > 0.f ? v : expm1f(v); o.z = g4.z * v + (1.f - g4.z) * f4.z;
    v = acc.w + b4.w; v = v > 0.f ? v : expm1f(v); o.w = g4.w * v + (1.f - g4.w) * f4.w;
    *(float4*)&out[base] = o;
}

// ---------------------------------------------------------------------------
extern "C" void kernel_launch(void* const* d_in, const int* in_sizes, int n_in,
                              void* d_out, int out_size, void* d_ws, size_t ws_size,
                              hipStream_t stream) {
    const float* feat  = (const float*)d_in[0];
    const int*   adj   = (const int*)  d_in[1];
    const float* W     = (const float*)d_in[2];
    const float* bvec  = (const float*)d_in[3];
    const float* wsrc  = (const float*)d_in[4];
    const float* wdst  = (const float*)d_in[5];
    const float* Hw    = (const float*)d_in[6];
    const float* Hb    = (const float*)d_in[7];
    float* out = (float*)d_out;

    const size_t H_SZ = (size_t)BB * AH * NN * EE;   // 3,145,728 floats
    const size_t G_SZ = (size_t)BB * NN * DIN;       // 3,145,728 floats
    const size_t S_SZ = (size_t)BB * AH * NN;        // 49,152 floats

    float* ws   = (float*)d_ws;
    float* Hbuf = ws;
    float* Gbuf = Hbuf + H_SZ;
    float* Sbuf = Gbuf + G_SZ;
    float* Dbuf = Sbuf + S_SZ;

    gemm_h_kernel<<<dim3(AH, MM / TILE), 256, 0, stream>>>(feat, W, Hbuf);
    gemm_gate_kernel<<<dim3(DIN / TILE, MM / TILE), 256, 0, stream>>>(feat, Hw, Hb, Gbuf);
    src_dst_kernel<<<(BB * AH * NN) / 4, 256, 0, stream>>>(Hbuf, wsrc, wdst, Sbuf, Dbuf);
    attn_kernel<<<dim3(NN / 16, BB * AH), 256, 0, stream>>>(Hbuf, Sbuf, Dbuf, adj, bvec, Gbuf, feat, out);
}

// Round 6
// 332.703 us; speedup vs baseline: 1.1667x; 1.1667x over previous
//
#include <hip/hip_runtime.h>
#include <hip/hip_bf16.h>

#define BB 8
#define NN 512
#define AH 12
#define DIN 768
#define EE 64
#define MM (BB*NN)          // 4096
#define YY (BB*AH)          // 96
#define LEAKY 0.2f

typedef unsigned short u16;
typedef unsigned int u32;
typedef __attribute__((ext_vector_type(8))) short short8;
typedef __attribute__((ext_vector_type(4))) float f32x4;

// float -> bf16 RNE
static __device__ __forceinline__ u16 f2bf(float f) {
    u32 u = __builtin_bit_cast(u32, f);
    u32 r = (u + 0x7FFFu + ((u >> 16) & 1u)) >> 16;
    return (u16)r;
}

// ---------------------------------------------------------------------------
// Hardware C/D-layout probe. Build synthetic fragments with the SAME
// (quad,x,j) -> (row, k) convention the real GEMM load path uses:
//   A-frag element j of lane (q,x) = A[x][q*8+j];  B-frag = Bt[x][q*8+j].
// With A[m][k] = m*16+k (k<16) and Bt = I, D[m][n] = m*16+n, so each
// accumulator register discloses its memory-space (row, col) directly.
// Valid under any internal lane permutation / shared k-relocation.
// ---------------------------------------------------------------------------
static __device__ __forceinline__ void mfma_probe(int lane, int* prow, int* pcol) {
    int q = lane >> 4, x = lane & 15;
    short8 af, bf;
#pragma unroll
    for (int j = 0; j < 8; j++) {
        int k = q * 8 + j;
        af[j] = (short)f2bf((k < 16) ? (float)(x * 16 + k) : 0.f);
        bf[j] = (short)f2bf((k == x) ? 1.f : 0.f);
    }
    f32x4 d = {};
    d = __builtin_amdgcn_mfma_f32_16x16x32_bf16(af, bf, d, 0, 0, 0);
#pragma unroll
    for (int r = 0; r < 4; r++) {
        int v = (int)(d[r] + 0.5f);
        prow[r] = v >> 4;
        pcol[r] = v & 15;
    }
}

// ---------------------------------------------------------------------------
// bf16 conversions. featb [4096][768]; Wt [12][64][768] (transposed);
// Hwb [768][768] (row o, col d, unchanged).
// ---------------------------------------------------------------------------
#define N_FEAT (MM*DIN)            // 3145728
#define N_W    (AH*DIN*EE)         // 589824
__global__ __launch_bounds__(256) void convert_kernel(const float* __restrict__ feat,
                                                      const float* __restrict__ W,
                                                      const float* __restrict__ Hw,
                                                      u16* __restrict__ featb,
                                                      u16* __restrict__ Wt,
                                                      u16* __restrict__ Hwb) {
    int i = blockIdx.x * 256 + threadIdx.x;
    if (i < N_FEAT) { featb[i] = f2bf(feat[i]); return; }
    int i2 = i - N_FEAT;
    if (i2 < N_W) {
        int a = i2 / (DIN * EE), rem = i2 % (DIN * EE);
        int e = rem / DIN, d = rem % DIN;
        Wt[i2] = f2bf(W[a * (DIN * EE) + d * EE + e]);
        return;
    }
    int i3 = i2 - N_W;
    Hwb[i3] = f2bf(Hw[i3]);
}

// ---------------------------------------------------------------------------
// GEMM h (MFMA): h = feat @ W[a]. Writes fp32 Hbuf [y][n][e].
// Writeback indices come from the hardware probe — no layout assumption.
// ---------------------------------------------------------------------------
__global__ __launch_bounds__(256) void gemm_h_kernel(const u16* __restrict__ featb,
                                                     const u16* __restrict__ Wt,
                                                     float* __restrict__ Hbuf) {
    int t = threadIdx.x, w = t >> 6, lane = t & 63, q = lane >> 4, x = lane & 15;
    int a = blockIdx.y, m0 = blockIdx.x * 64;
    int row = m0 + w * 16 + x;

    const u16* Ap = featb + row * DIN + q * 8;
    const u16* Bp = Wt + a * (DIN * EE) + x * DIN + q * 8;
    f32x4 acc[4] = {};

#pragma unroll 4
    for (int k0 = 0; k0 < DIN; k0 += 32) {
        short8 af = *(const short8*)(Ap + k0);
        short8 b0 = *(const short8*)(Bp + k0);
        short8 b1 = *(const short8*)(Bp + 16 * DIN + k0);
        short8 b2 = *(const short8*)(Bp + 32 * DIN + k0);
        short8 b3 = *(const short8*)(Bp + 48 * DIN + k0);
        acc[0] = __builtin_amdgcn_mfma_f32_16x16x32_bf16(af, b0, acc[0], 0, 0, 0);
        acc[1] = __builtin_amdgcn_mfma_f32_16x16x32_bf16(af, b1, acc[1], 0, 0, 0);
        acc[2] = __builtin_amdgcn_mfma_f32_16x16x32_bf16(af, b2, acc[2], 0, 0, 0);
        acc[3] = __builtin_amdgcn_mfma_f32_16x16x32_bf16(af, b3, acc[3], 0, 0, 0);
    }

    int prow[4], pcol[4];
    mfma_probe(lane, prow, pcol);

    int b = m0 >> 9;
    int y = b * AH + a;
    int nbase = (m0 & 511) + w * 16;

#pragma unroll
    for (int nt = 0; nt < 4; nt++)
#pragma unroll
        for (int r = 0; r < 4; r++)
            Hbuf[((size_t)y * NN + nbase + prow[r]) * EE + nt * 16 + pcol[r]] = acc[nt][r];
}

// ---------------------------------------------------------------------------
// src/dst (ROUND-1 VERBATIM): one wave per (b,a,n) row.
// ---------------------------------------------------------------------------
__global__ __launch_bounds__(256) void src_dst_kernel(const float* __restrict__ H,
                                                      const float* __restrict__ wsrc,
                                                      const float* __restrict__ wdst,
                                                      float* __restrict__ srcb,
                                                      float* __restrict__ dstb) {
    int t = threadIdx.x;
    int wave = t >> 6, lane = t & 63;
    int R = (blockIdx.x << 2) + wave;        // row in [0, B*A*N)
    int a = (R >> 9) % AH;
    float th = tanhf(H[(R << 6) + lane]);
    float s = th * wsrc[(a << 6) + lane];
    float d = th * wdst[(a << 6) + lane];
#pragma unroll
    for (int off = 32; off >= 1; off >>= 1) {
        s += __shfl_down(s, off);
        d += __shfl_down(d, off);
    }
    if (lane == 0) { srcb[R] = s; dstb[R] = d; }
}

// ---------------------------------------------------------------------------
// Attention (ROUND-1 VERBATIM minus gate blend): block = 16 rows x (b,a).
// ---------------------------------------------------------------------------
__global__ __launch_bounds__(256) void attn_kernel(const float* __restrict__ Hbuf,
                                                   const float* __restrict__ srcb,
                                                   const float* __restrict__ dstb,
                                                   const int* __restrict__ adj,
                                                   const float* __restrict__ bias,
                                                   float* __restrict__ out) {
    __shared__ float sdst[NN];
    __shared__ float ssrc[16];
    __shared__ unsigned smask[16][16];
    __shared__ float red[256];
    __shared__ float sm[16], sinvl[16];
    __shared__ int suni[16];
    __shared__ alignas(16) float h_s[128][64];
    __shared__ float p_s[16][132];

    int t = threadIdx.x;
    int y = blockIdx.y;                 // b*12 + a
    int i0 = blockIdx.x << 4;
    int bb = y / AH, a = y % AH;
    int ybase = y << 9;

    sdst[t]       = dstb[ybase + t];
    sdst[t + 256] = dstb[ybase + 256 + t];
    if (t < 16) ssrc[t] = srcb[ybase + i0 + t];

    // pack adjacency rows into bitmask (wave-wide ballot)
    const int* adjrow = adj + ((bb << 9) + i0) * NN;
#pragma unroll
    for (int it = 0; it < 32; it++) {
        int g = (it << 8) + t;
        int r = g >> 9, j = g & 511;
        int av = adjrow[(r << 9) + j];
        unsigned long long bal = __ballot(av != 0);
        if ((t & 63) == 0) {
            smask[r][j >> 5]       = (unsigned)bal;
            smask[r][(j >> 5) + 1] = (unsigned)(bal >> 32);
        }
    }
    __syncthreads();

    int r = t >> 4, sub = t & 15;
    float srcv = ssrc[r];

    // pass 1: row max over unmasked
    float lm = -1e30f;
    for (int jj = 0; jj < 32; jj++) {
        int j = sub + (jj << 4);
        if ((smask[r][j >> 5] >> (j & 31)) & 1) {
            float v = srcv + sdst[j];
            v = v >= 0.f ? v : LEAKY * v;
            lm = fmaxf(lm, v);
        }
    }
    red[t] = lm; __syncthreads();
    for (int off = 8; off; off >>= 1) {
        if (sub < off) red[t] = fmaxf(red[t], red[t + off]);
        __syncthreads();
    }
    float m_r = red[r << 4];
    __syncthreads();

    // pass 2: row sum of exp
    float ls = 0.f;
    for (int jj = 0; jj < 32; jj++) {
        int j = sub + (jj << 4);
        if ((smask[r][j >> 5] >> (j & 31)) & 1) {
            float v = srcv + sdst[j];
            v = v >= 0.f ? v : LEAKY * v;
            ls += expf(v - m_r);
        }
    }
    red[t] = ls; __syncthreads();
    for (int off = 8; off; off >>= 1) {
        if (sub < off) red[t] += red[t + off];
        __syncthreads();
    }
    if (sub == 0) {
        int uni = (m_r < -1e29f);        // no unmasked neighbors -> uniform 1/512
        suni[r] = uni;
        sm[r] = m_r;
        sinvl[r] = uni ? 0.f : 1.f / red[r << 4];
    }
    __syncthreads();

    // PV: thread = (row r, 4 cols e4..e4+3)
    float4 acc = {0.f, 0.f, 0.f, 0.f};
    int e4 = (t & 15) << 2;
    const float* hbase = Hbuf + ((long long)ybase << 6);

    for (int jt = 0; jt < 4; jt++) {
        int jb = jt << 7;
        // stage h tile [128][64]
#pragma unroll
        for (int q = 0; q < 8; q++) {
            int idx = (q << 8) + t;
            int jr = idx >> 4, ec = (idx & 15) << 2;
            *(float4*)&h_s[jr][ec] = *(const float4*)&hbase[((jb + jr) << 6) + ec];
        }
        // probability tile [16][128]
        {
            int js = (t & 15) << 3;
            float mm = sm[r]; float il = sinvl[r]; int uni = suni[r];
#pragma unroll
            for (int q = 0; q < 8; q++) {
                int jl = js + q, jg = jb + jl;
                float p;
                if (uni) p = (1.0f / 512.0f);
                else if ((smask[r][jg >> 5] >> (jg & 31)) & 1) {
                    float v = srcv + sdst[jg];
                    v = v >= 0.f ? v : LEAKY * v;
                    p = expf(v - mm) * il;
                } else p = 0.f;
                p_s[r][jl] = p;
            }
        }
        __syncthreads();
#pragma unroll 4
        for (int j = 0; j < 128; j++) {
            float4 hv = *(const float4*)&h_s[j][e4];
            float pv = p_s[r][j];
            acc.x += pv * hv.x; acc.y += pv * hv.y;
            acc.z += pv * hv.z; acc.w += pv * hv.w;
        }
        __syncthreads();
    }

    // epilogue: +bias, elu (gate blend in gemm_gate_kernel)
    int node = i0 + r;
    int base = ((bb << 9) + node) * DIN + (a << 6) + e4;
    float4 b4 = *(const float4*)&bias[e4];
    float4 o;
    float v;
    v = acc.x + b4.x; o.x = v > 0.f ? v : expm1f(v);
    v = acc.y + b4.y; o.y = v > 0.f ? v : expm1f(v);
    v = acc.z + b4.z; o.z = v > 0.f ? v : expm1f(v);
    v = acc.w + b4.w; o.w = v > 0.f ? v : expm1f(v);
    *(float4*)&out[base] = o;
}

// ---------------------------------------------------------------------------
// GEMM gate (MFMA, probe-indexed C staging) + fused sigmoid/blend epilogue.
// ---------------------------------------------------------------------------
static __device__ __forceinline__ float sigm(float z) {
    z = fminf(fmaxf(z, -80.f), 80.f);
    return 1.f / (1.f + __expf(-z));
}
__global__ __launch_bounds__(256) void gemm_gate_kernel(const u16* __restrict__ featb,
                                                        const u16* __restrict__ Hwb,
                                                        const float* __restrict__ Hb,
                                                        const float* __restrict__ feat,
                                                        float* __restrict__ out) {
    __shared__ alignas(16) float cs[64][68];
    int t = threadIdx.x, w = t >> 6, lane = t & 63, q = lane >> 4, x = lane & 15;
    int m0 = blockIdx.x * 64, n0 = blockIdx.y * 64;

    const u16* Ap = featb + (m0 + w * 16 + x) * DIN + q * 8;
    const u16* Bp = Hwb + (n0 + x) * DIN + q * 8;
    f32x4 acc[4] = {};

#pragma unroll 4
    for (int k0 = 0; k0 < DIN; k0 += 32) {
        short8 af = *(const short8*)(Ap + k0);
        short8 b0 = *(const short8*)(Bp + k0);
        short8 b1 = *(const short8*)(Bp + 16 * DIN + k0);
        short8 b2 = *(const short8*)(Bp + 32 * DIN + k0);
        short8 b3 = *(const short8*)(Bp + 48 * DIN + k0);
        acc[0] = __builtin_amdgcn_mfma_f32_16x16x32_bf16(af, b0, acc[0], 0, 0, 0);
        acc[1] = __builtin_amdgcn_mfma_f32_16x16x32_bf16(af, b1, acc[1], 0, 0, 0);
        acc[2] = __builtin_amdgcn_mfma_f32_16x16x32_bf16(af, b2, acc[2], 0, 0, 0);
        acc[3] = __builtin_amdgcn_mfma_f32_16x16x32_bf16(af, b3, acc[3], 0, 0, 0);
    }

    int prow[4], pcol[4];
    mfma_probe(lane, prow, pcol);

#pragma unroll
    for (int nt = 0; nt < 4; nt++)
#pragma unroll
        for (int r = 0; r < 4; r++)
            cs[w * 16 + prow[r]][nt * 16 + pcol[r]] = acc[nt][r];
    __syncthreads();

    float4 hb = *(const float4*)&Hb[n0 + (t & 15) * 4];
#pragma unroll
    for (int p = 0; p < 4; p++) {
        int ml = p * 16 + (t >> 4), c4 = (t & 15) * 4;
        float4 v4 = *(const float4*)&cs[ml][c4];
        size_t idx = (size_t)(m0 + ml) * DIN + n0 + c4;
        float4 fo = *(const float4*)&out[idx];
        float4 f4 = *(const float4*)&feat[idx];
        float4 o;
        float g;
        g = sigm(v4.x + hb.x); o.x = g * fo.x + (1.f - g) * f4.x;
        g = sigm(v4.y + hb.y); o.y = g * fo.y + (1.f - g) * f4.y;
        g = sigm(v4.z + hb.z); o.z = g * fo.z + (1.f - g) * f4.z;
        g = sigm(v4.w + hb.w); o.w = g * fo.w + (1.f - g) * f4.w;
        *(float4*)&out[idx] = o;
    }
}

// ---------------------------------------------------------------------------
extern "C" void kernel_launch(void* const* d_in, const int* in_sizes, int n_in,
                              void* d_out, int out_size, void* d_ws, size_t ws_size,
                              hipStream_t stream) {
    const float* feat  = (const float*)d_in[0];
    const int*   adj   = (const int*)  d_in[1];
    const float* W     = (const float*)d_in[2];
    const float* bvec  = (const float*)d_in[3];
    const float* wsrc  = (const float*)d_in[4];
    const float* wdst  = (const float*)d_in[5];
    const float* Hw    = (const float*)d_in[6];
    const float* Hb    = (const float*)d_in[7];
    float* out = (float*)d_out;

    char* ws = (char*)d_ws;
    u16*  featb = (u16*)(ws);                       // 6,291,456 B
    u16*  Wt    = (u16*)(ws + 6291456);             // 1,179,648 B
    u16*  Hwb   = (u16*)(ws + 7471104);             // 1,179,648 B
    float* Hbuf = (float*)(ws + 8650752);           // 12,582,912 B (fp32 h)
    float* Sbuf = (float*)(ws + 21233664);          //    196,608 B
    float* Dbuf = (float*)(ws + 21430272);          //    196,608 B

    convert_kernel<<<(N_FEAT + 2 * N_W) / 256, 256, 0, stream>>>(feat, W, Hw, featb, Wt, Hwb);
    gemm_h_kernel<<<dim3(MM / 64, AH), 256, 0, stream>>>(featb, Wt, Hbuf);
    src_dst_kernel<<<(BB * AH * NN) / 4, 256, 0, stream>>>(Hbuf, wsrc, wdst, Sbuf, Dbuf);
    attn_kernel<<<dim3(NN / 16, YY), 256, 0, stream>>>(Hbuf, Sbuf, Dbuf, adj, bvec, out);
    gemm_gate_kernel<<<dim3(MM / 64, DIN / 64), 256, 0, stream>>>(featb, Hwb, Hb, feat, out);
}

// Round 7
// 219.000 us; speedup vs baseline: 1.7725x; 1.5192x over previous
//
#include <hip/hip_runtime.h>
#include <hip/hip_bf16.h>

#define BB 8
#define NN 512
#define AH 12
#define DIN 768
#define EE 64
#define MM (BB*NN)          // 4096
#define YY (BB*AH)          // 96
#define LEAKY 0.2f

typedef unsigned short u16;
typedef unsigned int u32;
typedef __attribute__((ext_vector_type(8))) short short8;
typedef __attribute__((ext_vector_type(4))) float f32x4;

// float -> bf16 RNE
static __device__ __forceinline__ u16 f2bf(float f) {
    u32 u = __builtin_bit_cast(u32, f);
    u32 r = (u + 0x7FFFu + ((u >> 16) & 1u)) >> 16;
    return (u16)r;
}
static __device__ __forceinline__ u32 pk2(float a, float b) {
    return (u32)f2bf(a) | ((u32)f2bf(b) << 16);
}

// ---------------------------------------------------------------------------
// Hardware C/D-layout probe (validated round 6). Same load convention as all
// MFMA call sites: frag element j of lane (q,x) = M[x][q*8+j]. Discloses the
// memory-space (row, col) of each accumulator register.
// ---------------------------------------------------------------------------
static __device__ __forceinline__ void mfma_probe(int lane, int* prow, int* pcol) {
    int q = lane >> 4, x = lane & 15;
    short8 af, bf;
#pragma unroll
    for (int j = 0; j < 8; j++) {
        int k = q * 8 + j;
        af[j] = (short)f2bf((k < 16) ? (float)(x * 16 + k) : 0.f);
        bf[j] = (short)f2bf((k == x) ? 1.f : 0.f);
    }
    f32x4 d = {};
    d = __builtin_amdgcn_mfma_f32_16x16x32_bf16(af, bf, d, 0, 0, 0);
#pragma unroll
    for (int r = 0; r < 4; r++) {
        int v = (int)(d[r] + 0.5f);
        prow[r] = v >> 4;
        pcol[r] = v & 15;
    }
}

// ---------------------------------------------------------------------------
// Pack adjacency rows (512 ints) into 16-word bitmasks, once.
// ---------------------------------------------------------------------------
__global__ __launch_bounds__(256) void pack_adj_kernel(const int* __restrict__ adj,
                                                       u32* __restrict__ maskbuf) {
    int t = threadIdx.x, w = t >> 6, ln = t & 63;
    int row = blockIdx.x * 4 + w;              // 0..4095  (= b*512 + i)
    const int* ar = adj + (size_t)row * NN;
#pragma unroll
    for (int it = 0; it < 8; it++) {
        unsigned long long bal = __ballot(ar[it * 64 + ln] != 0);
        if (ln == 0) {
            maskbuf[row * 16 + it * 2]     = (u32)bal;
            maskbuf[row * 16 + it * 2 + 1] = (u32)(bal >> 32);
        }
    }
}

// ---------------------------------------------------------------------------
// bf16 conversions. featb [4096][768]; Wt [12][64][768] (transposed);
// Hwb [768][768] (row o, col d, unchanged).
// ---------------------------------------------------------------------------
#define N_FEAT (MM*DIN)            // 3145728
#define N_W    (AH*DIN*EE)         // 589824
__global__ __launch_bounds__(256) void convert_kernel(const float* __restrict__ feat,
                                                      const float* __restrict__ W,
                                                      const float* __restrict__ Hw,
                                                      u16* __restrict__ featb,
                                                      u16* __restrict__ Wt,
                                                      u16* __restrict__ Hwb) {
    int i = blockIdx.x * 256 + threadIdx.x;
    if (i < N_FEAT) { featb[i] = f2bf(feat[i]); return; }
    int i2 = i - N_FEAT;
    if (i2 < N_W) {
        int a = i2 / (DIN * EE), rem = i2 % (DIN * EE);
        int e = rem / DIN, d = rem % DIN;
        Wt[i2] = f2bf(W[a * (DIN * EE) + d * EE + e]);
        return;
    }
    int i3 = i2 - N_W;
    Hwb[i3] = f2bf(Hw[i3]);
}

// ---------------------------------------------------------------------------
// GEMM h (MFMA, probe writeback): h = feat @ W[a].
// Stages fp32 C tile to LDS, then (a) writes bf16 hT [y][e][n] coalesced,
// (b) fused tanh/src/dst reduction from the fp32 tile.
// ---------------------------------------------------------------------------
__global__ __launch_bounds__(256) void gemm_h_kernel(const u16* __restrict__ featb,
                                                     const u16* __restrict__ Wt,
                                                     const float* __restrict__ wsrc,
                                                     const float* __restrict__ wdst,
                                                     u16* __restrict__ hT,
                                                     float* __restrict__ Sbuf,
                                                     float* __restrict__ Dbuf) {
    __shared__ float cs[64][65];
    int t = threadIdx.x, w = t >> 6, lane = t & 63, q = lane >> 4, x = lane & 15;
    int a = blockIdx.y, m0 = blockIdx.x * 64;
    int row = m0 + w * 16 + x;

    const u16* Ap = featb + row * DIN + q * 8;
    const u16* Bp = Wt + a * (DIN * EE) + x * DIN + q * 8;
    f32x4 acc[4] = {};

#pragma unroll 4
    for (int k0 = 0; k0 < DIN; k0 += 32) {
        short8 af = *(const short8*)(Ap + k0);
        short8 b0 = *(const short8*)(Bp + k0);
        short8 b1 = *(const short8*)(Bp + 16 * DIN + k0);
        short8 b2 = *(const short8*)(Bp + 32 * DIN + k0);
        short8 b3 = *(const short8*)(Bp + 48 * DIN + k0);
        acc[0] = __builtin_amdgcn_mfma_f32_16x16x32_bf16(af, b0, acc[0], 0, 0, 0);
        acc[1] = __builtin_amdgcn_mfma_f32_16x16x32_bf16(af, b1, acc[1], 0, 0, 0);
        acc[2] = __builtin_amdgcn_mfma_f32_16x16x32_bf16(af, b2, acc[2], 0, 0, 0);
        acc[3] = __builtin_amdgcn_mfma_f32_16x16x32_bf16(af, b3, acc[3], 0, 0, 0);
    }

    int prow[4], pcol[4];
    mfma_probe(lane, prow, pcol);
#pragma unroll
    for (int nt = 0; nt < 4; nt++)
#pragma unroll
        for (int r = 0; r < 4; r++)
            cs[w * 16 + prow[r]][nt * 16 + pcol[r]] = acc[nt][r];
    __syncthreads();

    int b = m0 >> 9;
    int y = b * AH + a;
    int nbase = (m0 & 511);

    // (a) hT [y][e][nbase..+63] bf16, packed pairs
    {
        int e = t >> 2, ng = t & 3;
        u32* dst = (u32*)&hT[((size_t)y * EE + e) * NN + nbase + ng * 16];
#pragma unroll
        for (int i = 0; i < 8; i++)
            dst[i] = pk2(cs[ng * 16 + 2 * i][e], cs[ng * 16 + 2 * i + 1][e]);
    }
    // (b) fused src/dst: s[n] = sum_e tanh(h[n][e]) * wsrc[a][e]
    {
        int r = t >> 2, cg = t & 3;
        float s = 0.f, d = 0.f;
#pragma unroll
        for (int i = 0; i < 16; i++) {
            int e2 = cg * 16 + i;
            float th = tanhf(cs[r][e2]);
            s += th * wsrc[a * EE + e2];
            d += th * wdst[a * EE + e2];
        }
        s += __shfl_xor(s, 1); s += __shfl_xor(s, 2);
        d += __shfl_xor(d, 1); d += __shfl_xor(d, 2);
        if (cg == 0) {
            Sbuf[y * NN + nbase + r] = s;
            Dbuf[y * NN + nbase + r] = d;
        }
    }
}

// ---------------------------------------------------------------------------
// Attention (MFMA PV, probe writeback): block = 64 query rows x one (b,a).
// P fragments built in registers in the validated A convention. Clamped exp.
// ---------------------------------------------------------------------------
__global__ __launch_bounds__(256) void attn_kernel(const u16* __restrict__ hT,
                                                   const float* __restrict__ Sbuf,
                                                   const float* __restrict__ Dbuf,
                                                   const u32* __restrict__ maskbuf,
                                                   const float* __restrict__ bias,
                                                   float* __restrict__ out) {
    __shared__ alignas(16) float sdst[NN];
    __shared__ u32 smask[64][17];
    __shared__ float sm[64], sil[64];
    __shared__ int sun[64];
    __shared__ alignas(16) float cs[64][68];

    int t = threadIdx.x;
    int y = blockIdx.y, bb = y / AH, a = y % AH;
    int i0 = blockIdx.x * 64;

    sdst[t] = Dbuf[y * NN + t];
    sdst[t + 256] = Dbuf[y * NN + 256 + t];
#pragma unroll
    for (int p = 0; p < 4; p++) {
        int idx = p * 256 + t, r = idx >> 4, c = idx & 15;
        smask[r][c] = maskbuf[((bb << 9) + i0 + r) * 16 + c];
    }
    __syncthreads();

    // ---- softmax stats: 4 threads per row (clamped, inf-free) ----
    {
        int r = t >> 2, l4 = t & 3;
        float lmax = -1e30f;
#pragma unroll
        for (int cc = 0; cc < 4; cc++) {
            int c = l4 * 4 + cc;
            u32 mw = smask[r][c];
            for (int bit = 0; bit < 32; bit++) {
                float v = sdst[c * 32 + bit];
                if ((mw >> bit) & 1) lmax = fmaxf(lmax, v);
            }
        }
        lmax = fmaxf(lmax, __shfl_xor(lmax, 1));
        lmax = fmaxf(lmax, __shfl_xor(lmax, 2));
        float srcr = Sbuf[y * NN + i0 + r];
        int uni = lmax < -1e29f;
        float vm = srcr + lmax;
        float m_r = fmaxf(vm, LEAKY * vm);     // leaky monotone -> true row max
        if (uni) m_r = 0.f;
        float ls = 0.f;
#pragma unroll
        for (int cc = 0; cc < 4; cc++) {
            int c = l4 * 4 + cc;
            u32 mw = smask[r][c];
            for (int bit = 0; bit < 32; bit++) {
                float v = srcr + sdst[c * 32 + bit];
                v = fmaxf(v, LEAKY * v);
                float e = __expf(fminf(v - m_r, 0.f));
                if ((mw >> bit) & 1) ls += e;
            }
        }
        ls += __shfl_xor(ls, 1);
        ls += __shfl_xor(ls, 2);
        if ((t & 3) == 0) {
            sm[r] = m_r;
            sil[r] = uni ? 0.f : 1.f / fmaxf(ls, 1e-30f);
            sun[r] = uni;
        }
    }
    __syncthreads();

    // ---- PV via MFMA ----
    int w = t >> 6, lane = t & 63, q = lane >> 4, x = lane & 15;
    int rowl = w * 16 + x;                      // A-convention row this lane supplies
    float srcv = Sbuf[y * NN + i0 + rowl];
    float m_r = sm[rowl], il = sil[rowl];
    int uni = sun[rowl];
    const u16* hTy = hT + (size_t)y * EE * NN;
    f32x4 acc[4] = {};

#pragma unroll 2
    for (int k0 = 0; k0 < NN; k0 += 32) {
        u32 mb = smask[rowl][k0 >> 5] >> (q * 8);
        float pv[8];
#pragma unroll
        for (int j = 0; j < 8; j++) {
            float v = srcv + sdst[k0 + q * 8 + j];
            v = fmaxf(v, LEAKY * v);
            float e = __expf(fminf(v - m_r, 0.f)) * il;  // in [0,1]
            float pm = ((mb >> j) & 1) ? e : 0.f;
            pv[j] = uni ? (1.0f / 512.0f) : pm;
        }
        short8 af;
        af[0] = (short)f2bf(pv[0]); af[1] = (short)f2bf(pv[1]);
        af[2] = (short)f2bf(pv[2]); af[3] = (short)f2bf(pv[3]);
        af[4] = (short)f2bf(pv[4]); af[5] = (short)f2bf(pv[5]);
        af[6] = (short)f2bf(pv[6]); af[7] = (short)f2bf(pv[7]);
        const u16* hp = hTy + (size_t)x * NN + k0 + q * 8;
        short8 b0 = *(const short8*)(hp);
        short8 b1 = *(const short8*)(hp + 16 * NN);
        short8 b2 = *(const short8*)(hp + 32 * NN);
        short8 b3 = *(const short8*)(hp + 48 * NN);
        acc[0] = __builtin_amdgcn_mfma_f32_16x16x32_bf16(af, b0, acc[0], 0, 0, 0);
        acc[1] = __builtin_amdgcn_mfma_f32_16x16x32_bf16(af, b1, acc[1], 0, 0, 0);
        acc[2] = __builtin_amdgcn_mfma_f32_16x16x32_bf16(af, b2, acc[2], 0, 0, 0);
        acc[3] = __builtin_amdgcn_mfma_f32_16x16x32_bf16(af, b3, acc[3], 0, 0, 0);
    }

    int prow[4], pcol[4];
    mfma_probe(lane, prow, pcol);
#pragma unroll
    for (int nt = 0; nt < 4; nt++)
#pragma unroll
        for (int r = 0; r < 4; r++)
            cs[w * 16 + prow[r]][nt * 16 + pcol[r]] = acc[nt][r];
    __syncthreads();

    float4 b4 = *(const float4*)&bias[(t & 15) * 4];
#pragma unroll
    for (int p = 0; p < 4; p++) {
        int nl = p * 16 + (t >> 4), e4 = (t & 15) * 4;
        float4 c4 = *(const float4*)&cs[nl][e4];
        float4 o;
        float v;
        v = c4.x + b4.x; o.x = v > 0.f ? v : __expf(v) - 1.f;
        v = c4.y + b4.y; o.y = v > 0.f ? v : __expf(v) - 1.f;
        v = c4.z + b4.z; o.z = v > 0.f ? v : __expf(v) - 1.f;
        v = c4.w + b4.w; o.w = v > 0.f ? v : __expf(v) - 1.f;
        *(float4*)&out[((size_t)(bb << 9) + i0 + nl) * DIN + a * EE + e4] = o;
    }
}

// ---------------------------------------------------------------------------
// GEMM gate (MFMA, probe writeback) + fused sigmoid/blend (verified round 6).
// ---------------------------------------------------------------------------
static __device__ __forceinline__ float sigm(float z) {
    z = fminf(fmaxf(z, -80.f), 80.f);
    return 1.f / (1.f + __expf(-z));
}
__global__ __launch_bounds__(256) void gemm_gate_kernel(const u16* __restrict__ featb,
                                                        const u16* __restrict__ Hwb,
                                                        const float* __restrict__ Hb,
                                                        const float* __restrict__ feat,
                                                        float* __restrict__ out) {
    __shared__ alignas(16) float cs[64][68];
    int t = threadIdx.x, w = t >> 6, lane = t & 63, q = lane >> 4, x = lane & 15;
    int m0 = blockIdx.x * 64, n0 = blockIdx.y * 64;

    const u16* Ap = featb + (m0 + w * 16 + x) * DIN + q * 8;
    const u16* Bp = Hwb + (n0 + x) * DIN + q * 8;
    f32x4 acc[4] = {};

#pragma unroll 4
    for (int k0 = 0; k0 < DIN; k0 += 32) {
        short8 af = *(const short8*)(Ap + k0);
        short8 b0 = *(const short8*)(Bp + k0);
        short8 b1 = *(const short8*)(Bp + 16 * DIN + k0);
        short8 b2 = *(const short8*)(Bp + 32 * DIN + k0);
        short8 b3 = *(const short8*)(Bp + 48 * DIN + k0);
        acc[0] = __builtin_amdgcn_mfma_f32_16x16x32_bf16(af, b0, acc[0], 0, 0, 0);
        acc[1] = __builtin_amdgcn_mfma_f32_16x16x32_bf16(af, b1, acc[1], 0, 0, 0);
        acc[2] = __builtin_amdgcn_mfma_f32_16x16x32_bf16(af, b2, acc[2], 0, 0, 0);
        acc[3] = __builtin_amdgcn_mfma_f32_16x16x32_bf16(af, b3, acc[3], 0, 0, 0);
    }

    int prow[4], pcol[4];
    mfma_probe(lane, prow, pcol);
#pragma unroll
    for (int nt = 0; nt < 4; nt++)
#pragma unroll
        for (int r = 0; r < 4; r++)
            cs[w * 16 + prow[r]][nt * 16 + pcol[r]] = acc[nt][r];
    __syncthreads();

    float4 hb = *(const float4*)&Hb[n0 + (t & 15) * 4];
#pragma unroll
    for (int p = 0; p < 4; p++) {
        int ml = p * 16 + (t >> 4), c4 = (t & 15) * 4;
        float4 v4 = *(const float4*)&cs[ml][c4];
        size_t idx = (size_t)(m0 + ml) * DIN + n0 + c4;
        float4 fo = *(const float4*)&out[idx];
        float4 f4 = *(const float4*)&feat[idx];
        float4 o;
        float g;
        g = sigm(v4.x + hb.x); o.x = g * fo.x + (1.f - g) * f4.x;
        g = sigm(v4.y + hb.y); o.y = g * fo.y + (1.f - g) * f4.y;
        g = sigm(v4.z + hb.z); o.z = g * fo.z + (1.f - g) * f4.z;
        g = sigm(v4.w + hb.w); o.w = g * fo.w + (1.f - g) * f4.w;
        *(float4*)&out[idx] = o;
    }
}

// ---------------------------------------------------------------------------
extern "C" void kernel_launch(void* const* d_in, const int* in_sizes, int n_in,
                              void* d_out, int out_size, void* d_ws, size_t ws_size,
                              hipStream_t stream) {
    const float* feat  = (const float*)d_in[0];
    const int*   adj   = (const int*)  d_in[1];
    const float* W     = (const float*)d_in[2];
    const float* bvec  = (const float*)d_in[3];
    const float* wsrc  = (const float*)d_in[4];
    const float* wdst  = (const float*)d_in[5];
    const float* Hw    = (const float*)d_in[6];
    const float* Hb    = (const float*)d_in[7];
    float* out = (float*)d_out;

    char* ws = (char*)d_ws;
    u16*  featb   = (u16*)(ws);                       // 6,291,456 B
    u16*  Wt      = (u16*)(ws + 6291456);             // 1,179,648 B
    u16*  Hwb     = (u16*)(ws + 7471104);             // 1,179,648 B
    u16*  hT      = (u16*)(ws + 8650752);             // 6,291,456 B
    float* Sbuf   = (float*)(ws + 14942208);          //   196,608 B
    float* Dbuf   = (float*)(ws + 15138816);          //   196,608 B
    u32*  maskbuf = (u32*)(ws + 15335424);            //   262,144 B

    pack_adj_kernel<<<MM / 4, 256, 0, stream>>>(adj, maskbuf);
    convert_kernel<<<(N_FEAT + 2 * N_W) / 256, 256, 0, stream>>>(feat, W, Hw, featb, Wt, Hwb);
    gemm_h_kernel<<<dim3(MM / 64, AH), 256, 0, stream>>>(featb, Wt, wsrc, wdst, hT, Sbuf, Dbuf);
    attn_kernel<<<dim3(NN / 64, YY), 256, 0, stream>>>(hT, Sbuf, Dbuf, maskbuf, bvec, out);
    gemm_gate_kernel<<<dim3(MM / 64, DIN / 64), 256, 0, stream>>>(featb, Hwb, Hb, feat, out);
}

// Round 8
// 157.943 us; speedup vs baseline: 2.4577x; 1.3866x over previous
//
#include <hip/hip_runtime.h>
#include <hip/hip_bf16.h>

#define BB 8
#define NN 512
#define AH 12
#define DIN 768
#define EE 64
#define MM (BB*NN)          // 4096
#define YY (BB*AH)          // 96
#define LEAKY 0.2f

typedef unsigned short u16;
typedef unsigned int u32;
typedef __attribute__((ext_vector_type(8))) short short8;
typedef __attribute__((ext_vector_type(4))) float f32x4;

// float -> bf16 RNE
static __device__ __forceinline__ u16 f2bf(float f) {
    u32 u = __builtin_bit_cast(u32, f);
    u32 r = (u + 0x7FFFu + ((u >> 16) & 1u)) >> 16;
    return (u16)r;
}
static __device__ __forceinline__ u32 pk2(float a, float b) {
    return (u32)f2bf(a) | ((u32)f2bf(b) << 16);
}
// fast tanh via exp2-based __expf; |x| clamped (h values |x|<~15 anyway)
static __device__ __forceinline__ float ftanh(float x) {
    x = fminf(fmaxf(x, -15.f), 15.f);
    return 1.f - 2.f / (__expf(2.f * x) + 1.f);
}
// async global->LDS, 16B per lane; LDS dest = wave-uniform base + lane*16
static __device__ __forceinline__ void gl_lds16(const u16* g, u16* l) {
    __builtin_amdgcn_global_load_lds((const __attribute__((address_space(1))) unsigned int*)g,
                                     (__attribute__((address_space(3))) unsigned int*)l,
                                     16, 0, 0);
}

// ---------------------------------------------------------------------------
// Hardware C/D-layout probe (validated round 6/7).
// ---------------------------------------------------------------------------
static __device__ __forceinline__ void mfma_probe(int lane, int* prow, int* pcol) {
    int q = lane >> 4, x = lane & 15;
    short8 af, bf;
#pragma unroll
    for (int j = 0; j < 8; j++) {
        int k = q * 8 + j;
        af[j] = (short)f2bf((k < 16) ? (float)(x * 16 + k) : 0.f);
        bf[j] = (short)f2bf((k == x) ? 1.f : 0.f);
    }
    f32x4 d = {};
    d = __builtin_amdgcn_mfma_f32_16x16x32_bf16(af, bf, d, 0, 0, 0);
#pragma unroll
    for (int r = 0; r < 4; r++) {
        int v = (int)(d[r] + 0.5f);
        prow[r] = v >> 4;
        pcol[r] = v & 15;
    }
}

// ---------------------------------------------------------------------------
// Pack adjacency rows into bitmasks (verified).
// ---------------------------------------------------------------------------
__global__ __launch_bounds__(256) void pack_adj_kernel(const int* __restrict__ adj,
                                                       u32* __restrict__ maskbuf) {
    int t = threadIdx.x, w = t >> 6, ln = t & 63;
    int row = blockIdx.x * 4 + w;
    const int* ar = adj + (size_t)row * NN;
#pragma unroll
    for (int it = 0; it < 8; it++) {
        unsigned long long bal = __ballot(ar[it * 64 + ln] != 0);
        if (ln == 0) {
            maskbuf[row * 16 + it * 2]     = (u32)bal;
            maskbuf[row * 16 + it * 2 + 1] = (u32)(bal >> 32);
        }
    }
}

// ---------------------------------------------------------------------------
// bf16 conversions (verified). Wt is a contiguous [768 n][768 k] Bt matrix.
// ---------------------------------------------------------------------------
#define N_FEAT (MM*DIN)            // 3145728
#define N_W    (AH*DIN*EE)         // 589824
__global__ __launch_bounds__(256) void convert_kernel(const float* __restrict__ feat,
                                                      const float* __restrict__ W,
                                                      const float* __restrict__ Hw,
                                                      u16* __restrict__ featb,
                                                      u16* __restrict__ Wt,
                                                      u16* __restrict__ Hwb) {
    int i = blockIdx.x * 256 + threadIdx.x;
    if (i < N_FEAT) { featb[i] = f2bf(feat[i]); return; }
    int i2 = i - N_FEAT;
    if (i2 < N_W) {
        int a = i2 / (DIN * EE), rem = i2 % (DIN * EE);
        int e = rem / DIN, d = rem % DIN;
        Wt[i2] = f2bf(W[a * (DIN * EE) + d * EE + e]);
        return;
    }
    int i3 = i2 - N_W;
    Hwb[i3] = f2bf(Hw[i3]);
}

// ---------------------------------------------------------------------------
// m97-style K-loop core: 64x64 C tile, BK=32, global_load_lds staging.
// As/Bs: [64 rows][32 k] bf16, unpadded (global_load_lds requires contiguity).
// Wave w computes 32x32 subtile (wm = w&1 rows, wn = w>>1 cols), 2x2 MFMA.
// ---------------------------------------------------------------------------
#define GEMM_CORE(Abase, Bbase)                                               \
    int wm = w & 1, wn = w >> 1;                                              \
    int srow = t >> 2, skoff = (t & 3) * 8;                                   \
    const u16* Agp = (Abase) + srow * DIN + skoff;                            \
    const u16* Bgp = (Bbase) + srow * DIN + skoff;                            \
    u16* Asw = As + w * 512;                                                  \
    u16* Bsw = Bs + w * 512;                                                  \
    const u16* ApA = As + (wm * 32 + x) * 32 + q * 8;                         \
    const u16* ApB = Bs + (wn * 32 + x) * 32 + q * 8;                         \
    f32x4 acc00 = {}, acc01 = {}, acc10 = {}, acc11 = {};                     \
    for (int k0 = 0; k0 < DIN; k0 += 32) {                                    \
        gl_lds16(Agp + k0, Asw);                                              \
        gl_lds16(Bgp + k0, Bsw);                                              \
        __syncthreads();                                                      \
        short8 a0 = *(const short8*)(ApA);                                    \
        short8 a1 = *(const short8*)(ApA + 16 * 32);                          \
        short8 b0 = *(const short8*)(ApB);                                    \
        short8 b1 = *(const short8*)(ApB + 16 * 32);                          \
        acc00 = __builtin_amdgcn_mfma_f32_16x16x32_bf16(a0, b0, acc00, 0, 0, 0); \
        acc01 = __builtin_amdgcn_mfma_f32_16x16x32_bf16(a0, b1, acc01, 0, 0, 0); \
        acc10 = __builtin_amdgcn_mfma_f32_16x16x32_bf16(a1, b0, acc10, 0, 0, 0); \
        acc11 = __builtin_amdgcn_mfma_f32_16x16x32_bf16(a1, b1, acc11, 0, 0, 0); \
        __syncthreads();                                                      \
    }                                                                         \
    int prow[4], pcol[4];                                                     \
    mfma_probe(lane, prow, pcol);                                             \
    _Pragma("unroll")                                                         \
    for (int r = 0; r < 4; r++) {                                             \
        cs[wm * 32 + prow[r]][wn * 32 + pcol[r]]           = acc00[r];        \
        cs[wm * 32 + prow[r]][wn * 32 + 16 + pcol[r]]      = acc01[r];        \
        cs[wm * 32 + 16 + prow[r]][wn * 32 + pcol[r]]      = acc10[r];        \
        cs[wm * 32 + 16 + prow[r]][wn * 32 + 16 + pcol[r]] = acc11[r];        \
    }                                                                         \
    __syncthreads();

// ---------------------------------------------------------------------------
// GEMM h: C tile = 64 nodes x 64 e (one head). Epilogue: bf16 hT [y][e][n]
// + fused tanh/src/dst reduction.
// ---------------------------------------------------------------------------
__global__ __launch_bounds__(256) void gemm_h_kernel(const u16* __restrict__ featb,
                                                     const u16* __restrict__ Wt,
                                                     const float* __restrict__ wsrc,
                                                     const float* __restrict__ wdst,
                                                     u16* __restrict__ hT,
                                                     float* __restrict__ Sbuf,
                                                     float* __restrict__ Dbuf) {
    __shared__ u16 As[64 * 32];
    __shared__ u16 Bs[64 * 32];
    __shared__ alignas(16) float cs[64][68];
    int t = threadIdx.x, w = t >> 6, lane = t & 63, q = lane >> 4, x = lane & 15;
    int m0 = blockIdx.x * 64, a = blockIdx.y;

    GEMM_CORE(featb + (size_t)m0 * DIN, Wt + (size_t)a * EE * DIN)

    int b = m0 >> 9;
    int y = b * AH + a;
    int nbase = m0 & 511;

    // (a) hT [y][e][nbase..+63] bf16
    {
        int e = t >> 2, ng = t & 3;
        u32* dst = (u32*)&hT[((size_t)y * EE + e) * NN + nbase + ng * 16];
#pragma unroll
        for (int i = 0; i < 8; i++)
            dst[i] = pk2(cs[ng * 16 + 2 * i][e], cs[ng * 16 + 2 * i + 1][e]);
    }
    // (b) fused src/dst
    {
        int r = t >> 2, cg = t & 3;
        float s = 0.f, d = 0.f;
#pragma unroll
        for (int i = 0; i < 16; i++) {
            int e2 = cg * 16 + i;
            float th = ftanh(cs[r][e2]);
            s += th * wsrc[a * EE + e2];
            d += th * wdst[a * EE + e2];
        }
        s += __shfl_xor(s, 1); s += __shfl_xor(s, 2);
        d += __shfl_xor(d, 1); d += __shfl_xor(d, 2);
        if (cg == 0) {
            Sbuf[y * NN + nbase + r] = s;
            Dbuf[y * NN + nbase + r] = d;
        }
    }
}

// ---------------------------------------------------------------------------
// GEMM gate: C tile = 64 rows x 64 gate-cols + fused sigmoid/blend.
// ---------------------------------------------------------------------------
static __device__ __forceinline__ float sigm(float z) {
    z = fminf(fmaxf(z, -80.f), 80.f);
    return 1.f / (1.f + __expf(-z));
}
__global__ __launch_bounds__(256) void gemm_gate_kernel(const u16* __restrict__ featb,
                                                        const u16* __restrict__ Hwb,
                                                        const float* __restrict__ Hb,
                                                        const float* __restrict__ feat,
                                                        float* __restrict__ out) {
    __shared__ u16 As[64 * 32];
    __shared__ u16 Bs[64 * 32];
    __shared__ alignas(16) float cs[64][68];
    int t = threadIdx.x, w = t >> 6, lane = t & 63, q = lane >> 4, x = lane & 15;
    int m0 = blockIdx.x * 64, n0 = blockIdx.y * 64;

    GEMM_CORE(featb + (size_t)m0 * DIN, Hwb + (size_t)n0 * DIN)

    float4 hb = *(const float4*)&Hb[n0 + (t & 15) * 4];
#pragma unroll
    for (int p = 0; p < 4; p++) {
        int ml = p * 16 + (t >> 4), c4 = (t & 15) * 4;
        float4 v4 = *(const float4*)&cs[ml][c4];
        size_t idx = (size_t)(m0 + ml) * DIN + n0 + c4;
        float4 fo = *(const float4*)&out[idx];
        float4 f4 = *(const float4*)&feat[idx];
        float4 o;
        float g;
        g = sigm(v4.x + hb.x); o.x = g * fo.x + (1.f - g) * f4.x;
        g = sigm(v4.y + hb.y); o.y = g * fo.y + (1.f - g) * f4.y;
        g = sigm(v4.z + hb.z); o.z = g * fo.z + (1.f - g) * f4.z;
        g = sigm(v4.w + hb.w); o.w = g * fo.w + (1.f - g) * f4.w;
        *(float4*)&out[idx] = o;
    }
}

// ---------------------------------------------------------------------------
// Attention (verified round 7, unchanged).
// ---------------------------------------------------------------------------
__global__ __launch_bounds__(256) void attn_kernel(const u16* __restrict__ hT,
                                                   const float* __restrict__ Sbuf,
                                                   const float* __restrict__ Dbuf,
                                                   const u32* __restrict__ maskbuf,
                                                   const float* __restrict__ bias,
                                                   float* __restrict__ out) {
    __shared__ alignas(16) float sdst[NN];
    __shared__ u32 smask[64][17];
    __shared__ float sm[64], sil[64];
    __shared__ int sun[64];
    __shared__ alignas(16) float cs[64][68];

    int t = threadIdx.x;
    int y = blockIdx.y, bb = y / AH, a = y % AH;
    int i0 = blockIdx.x * 64;

    sdst[t] = Dbuf[y * NN + t];
    sdst[t + 256] = Dbuf[y * NN + 256 + t];
#pragma unroll
    for (int p = 0; p < 4; p++) {
        int idx = p * 256 + t, r = idx >> 4, c = idx & 15;
        smask[r][c] = maskbuf[((bb << 9) + i0 + r) * 16 + c];
    }
    __syncthreads();

    {
        int r = t >> 2, l4 = t & 3;
        float lmax = -1e30f;
#pragma unroll
        for (int cc = 0; cc < 4; cc++) {
            int c = l4 * 4 + cc;
            u32 mw = smask[r][c];
            for (int bit = 0; bit < 32; bit++) {
                float v = sdst[c * 32 + bit];
                if ((mw >> bit) & 1) lmax = fmaxf(lmax, v);
            }
        }
        lmax = fmaxf(lmax, __shfl_xor(lmax, 1));
        lmax = fmaxf(lmax, __shfl_xor(lmax, 2));
        float srcr = Sbuf[y * NN + i0 + r];
        int uni = lmax < -1e29f;
        float vm = srcr + lmax;
        float m_r = fmaxf(vm, LEAKY * vm);
        if (uni) m_r = 0.f;
        float ls = 0.f;
#pragma unroll
        for (int cc = 0; cc < 4; cc++) {
            int c = l4 * 4 + cc;
            u32 mw = smask[r][c];
            for (int bit = 0; bit < 32; bit++) {
                float v = srcr + sdst[c * 32 + bit];
                v = fmaxf(v, LEAKY * v);
                float e = __expf(fminf(v - m_r, 0.f));
                if ((mw >> bit) & 1) ls += e;
            }
        }
        ls += __shfl_xor(ls, 1);
        ls += __shfl_xor(ls, 2);
        if ((t & 3) == 0) {
            sm[r] = m_r;
            sil[r] = uni ? 0.f : 1.f / fmaxf(ls, 1e-30f);
            sun[r] = uni;
        }
    }
    __syncthreads();

    int w = t >> 6, lane = t & 63, q = lane >> 4, x = lane & 15;
    int rowl = w * 16 + x;
    float srcv = Sbuf[y * NN + i0 + rowl];
    float m_r = sm[rowl], il = sil[rowl];
    int uni = sun[rowl];
    const u16* hTy = hT + (size_t)y * EE * NN;
    f32x4 acc[4] = {};

#pragma unroll 2
    for (int k0 = 0; k0 < NN; k0 += 32) {
        u32 mb = smask[rowl][k0 >> 5] >> (q * 8);
        float pv[8];
#pragma unroll
        for (int j = 0; j < 8; j++) {
            float v = srcv + sdst[k0 + q * 8 + j];
            v = fmaxf(v, LEAKY * v);
            float e = __expf(fminf(v - m_r, 0.f)) * il;
            float pm = ((mb >> j) & 1) ? e : 0.f;
            pv[j] = uni ? (1.0f / 512.0f) : pm;
        }
        short8 af;
        af[0] = (short)f2bf(pv[0]); af[1] = (short)f2bf(pv[1]);
        af[2] = (short)f2bf(pv[2]); af[3] = (short)f2bf(pv[3]);
        af[4] = (short)f2bf(pv[4]); af[5] = (short)f2bf(pv[5]);
        af[6] = (short)f2bf(pv[6]); af[7] = (short)f2bf(pv[7]);
        const u16* hp = hTy + (size_t)x * NN + k0 + q * 8;
        short8 b0 = *(const short8*)(hp);
        short8 b1 = *(const short8*)(hp + 16 * NN);
        short8 b2 = *(const short8*)(hp + 32 * NN);
        short8 b3 = *(const short8*)(hp + 48 * NN);
        acc[0] = __builtin_amdgcn_mfma_f32_16x16x32_bf16(af, b0, acc[0], 0, 0, 0);
        acc[1] = __builtin_amdgcn_mfma_f32_16x16x32_bf16(af, b1, acc[1], 0, 0, 0);
        acc[2] = __builtin_amdgcn_mfma_f32_16x16x32_bf16(af, b2, acc[2], 0, 0, 0);
        acc[3] = __builtin_amdgcn_mfma_f32_16x16x32_bf16(af, b3, acc[3], 0, 0, 0);
    }

    int prow[4], pcol[4];
    mfma_probe(lane, prow, pcol);
#pragma unroll
    for (int nt = 0; nt < 4; nt++)
#pragma unroll
        for (int r = 0; r < 4; r++)
            cs[w * 16 + prow[r]][nt * 16 + pcol[r]] = acc[nt][r];
    __syncthreads();

    float4 b4 = *(const float4*)&bias[(t & 15) * 4];
#pragma unroll
    for (int p = 0; p < 4; p++) {
        int nl = p * 16 + (t >> 4), e4 = (t & 15) * 4;
        float4 c4 = *(const float4*)&cs[nl][e4];
        float4 o;
        float v;
        v = c4.x + b4.x; o.x = v > 0.f ? v : __expf(v) - 1.f;
        v = c4.y + b4.y; o.y = v > 0.f ? v : __expf(v) - 1.f;
        v = c4.z + b4.z; o.z = v > 0.f ? v : __expf(v) - 1.f;
        v = c4.w + b4.w; o.w = v > 0.f ? v : __expf(v) - 1.f;
        *(float4*)&out[((size_t)(bb << 9) + i0 + nl) * DIN + a * EE + e4] = o;
    }
}

// ---------------------------------------------------------------------------
extern "C" void kernel_launch(void* const* d_in, const int* in_sizes, int n_in,
                              void* d_out, int out_size, void* d_ws, size_t ws_size,
                              hipStream_t stream) {
    const float* feat  = (const float*)d_in[0];
    const int*   adj   = (const int*)  d_in[1];
    const float* W     = (const float*)d_in[2];
    const float* bvec  = (const float*)d_in[3];
    const float* wsrc  = (const float*)d_in[4];
    const float* wdst  = (const float*)d_in[5];
    const float* Hw    = (const float*)d_in[6];
    const float* Hb    = (const float*)d_in[7];
    float* out = (float*)d_out;

    char* ws = (char*)d_ws;
    u16*  featb   = (u16*)(ws);                       // 6,291,456 B
    u16*  Wt      = (u16*)(ws + 6291456);             // 1,179,648 B
    u16*  Hwb     = (u16*)(ws + 7471104);             // 1,179,648 B
    u16*  hT      = (u16*)(ws + 8650752);             // 6,291,456 B
    float* Sbuf   = (float*)(ws + 14942208);          //   196,608 B
    float* Dbuf   = (float*)(ws + 15138816);          //   196,608 B
    u32*  maskbuf = (u32*)(ws + 15335424);            //   262,144 B

    pack_adj_kernel<<<MM / 4, 256, 0, stream>>>(adj, maskbuf);
    convert_kernel<<<(N_FEAT + 2 * N_W) / 256, 256, 0, stream>>>(feat, W, Hw, featb, Wt, Hwb);
    gemm_h_kernel<<<dim3(MM / 64, AH), 256, 0, stream>>>(featb, Wt, wsrc, wdst, hT, Sbuf, Dbuf);
    attn_kernel<<<dim3(NN / 64, YY), 256, 0, stream>>>(hT, Sbuf, Dbuf, maskbuf, bvec, out);
    gemm_gate_kernel<<<dim3(MM / 64, DIN / 64), 256, 0, stream>>>(featb, Hwb, Hb, feat, out);
}

// Round 9
// 145.327 us; speedup vs baseline: 2.6711x; 1.0868x over previous
//
#include <hip/hip_runtime.h>
#include <hip/hip_bf16.h>

#define BB 8
#define NN 512
#define AH 12
#define DIN 768
#define EE 64
#define MM (BB*NN)          // 4096
#define YY (BB*AH)          // 96
#define LEAKY 0.2f

typedef unsigned short u16;
typedef unsigned int u32;
typedef __attribute__((ext_vector_type(8))) short short8;
typedef __attribute__((ext_vector_type(4))) float f32x4;

// float -> bf16 RNE
static __device__ __forceinline__ u16 f2bf(float f) {
    u32 u = __builtin_bit_cast(u32, f);
    u32 r = (u + 0x7FFFu + ((u >> 16) & 1u)) >> 16;
    return (u16)r;
}
static __device__ __forceinline__ u32 pk2(float a, float b) {
    return (u32)f2bf(a) | ((u32)f2bf(b) << 16);
}
static __device__ __forceinline__ float ftanh(float x) {
    x = fminf(fmaxf(x, -15.f), 15.f);
    return 1.f - 2.f / (__expf(2.f * x) + 1.f);
}
// async global->LDS, 16B per lane; LDS dest = wave-uniform base + lane*16
static __device__ __forceinline__ void gl_lds16(const u16* g, u16* l) {
    __builtin_amdgcn_global_load_lds((const __attribute__((address_space(1))) unsigned int*)g,
                                     (__attribute__((address_space(3))) unsigned int*)l,
                                     16, 0, 0);
}

// ---------------------------------------------------------------------------
// Hardware C/D-layout probe (validated rounds 6-8).
// ---------------------------------------------------------------------------
static __device__ __forceinline__ void mfma_probe(int lane, int* prow, int* pcol) {
    int q = lane >> 4, x = lane & 15;
    short8 af, bf;
#pragma unroll
    for (int j = 0; j < 8; j++) {
        int k = q * 8 + j;
        af[j] = (short)f2bf((k < 16) ? (float)(x * 16 + k) : 0.f);
        bf[j] = (short)f2bf((k == x) ? 1.f : 0.f);
    }
    f32x4 d = {};
    d = __builtin_amdgcn_mfma_f32_16x16x32_bf16(af, bf, d, 0, 0, 0);
#pragma unroll
    for (int r = 0; r < 4; r++) {
        int v = (int)(d[r] + 0.5f);
        prow[r] = v >> 4;
        pcol[r] = v & 15;
    }
}

// ---------------------------------------------------------------------------
// Pack adjacency rows into bitmasks (verified).
// ---------------------------------------------------------------------------
__global__ __launch_bounds__(256) void pack_adj_kernel(const int* __restrict__ adj,
                                                       u32* __restrict__ maskbuf) {
    int t = threadIdx.x, w = t >> 6, ln = t & 63;
    int row = blockIdx.x * 4 + w;
    const int* ar = adj + (size_t)row * NN;
#pragma unroll
    for (int it = 0; it < 8; it++) {
        unsigned long long bal = __ballot(ar[it * 64 + ln] != 0);
        if (ln == 0) {
            maskbuf[row * 16 + it * 2]     = (u32)bal;
            maskbuf[row * 16 + it * 2 + 1] = (u32)(bal >> 32);
        }
    }
}

// ---------------------------------------------------------------------------
// bf16 conversions (verified).
// ---------------------------------------------------------------------------
#define N_FEAT (MM*DIN)            // 3145728
#define N_W    (AH*DIN*EE)         // 589824
__global__ __launch_bounds__(256) void convert_kernel(const float* __restrict__ feat,
                                                      const float* __restrict__ W,
                                                      const float* __restrict__ Hw,
                                                      u16* __restrict__ featb,
                                                      u16* __restrict__ Wt,
                                                      u16* __restrict__ Hwb) {
    int i = blockIdx.x * 256 + threadIdx.x;
    if (i < N_FEAT) { featb[i] = f2bf(feat[i]); return; }
    int i2 = i - N_FEAT;
    if (i2 < N_W) {
        int a = i2 / (DIN * EE), rem = i2 % (DIN * EE);
        int e = rem / DIN, d = rem % DIN;
        Wt[i2] = f2bf(W[a * (DIN * EE) + d * EE + e]);
        return;
    }
    int i3 = i2 - N_W;
    Hwb[i3] = f2bf(Hw[i3]);
}

// ---------------------------------------------------------------------------
// K-loop core: 64x64 C tile, BK=64, global_load_lds staging, XOR k-swizzle.
// LDS tile [64 rows][64 k]; row r's k-chunk j8 (8 u16) lives at col8 = j8^(r&7)
// (swizzle keeps ds_read_b128 at 8-way instead of 16-way on 128-B rows).
// Staging: thread t loads global (row t>>3, k-chunk (t&7)^( (t>>3)&7 )).
// Wave w computes 32x32 subtile (wm=w&1, wn=w>>1), 2x2 MFMA x 2 k-chunks.
// ---------------------------------------------------------------------------
#define GEMM_CORE(Abase, Bbase)                                               \
    int wm = w & 1, wn = w >> 1, xr = x & 7;                                  \
    int srow = t >> 3;                                                        \
    int skoff = ((t & 7) ^ (srow & 7)) * 8;                                   \
    const u16* Agp = (Abase) + srow * DIN + skoff;                            \
    const u16* Bgp = (Bbase) + srow * DIN + skoff;                            \
    u16* Asw = As + w * 512;                                                  \
    u16* Bsw = Bs + w * 512;                                                  \
    const u16* ApA = As + (wm * 32 + x) * 64;                                 \
    const u16* ApB = Bs + (wn * 32 + x) * 64;                                 \
    f32x4 acc00 = {}, acc01 = {}, acc10 = {}, acc11 = {};                     \
    for (int k0 = 0; k0 < DIN; k0 += 64) {                                    \
        gl_lds16(Agp + k0, Asw);                                              \
        gl_lds16(Agp + 32 * DIN + k0, Asw + 2048);                            \
        gl_lds16(Bgp + k0, Bsw);                                              \
        gl_lds16(Bgp + 32 * DIN + k0, Bsw + 2048);                            \
        __syncthreads();                                                      \
        _Pragma("unroll")                                                     \
        for (int kk = 0; kk < 2; kk++) {                                      \
            int c8 = ((q + kk * 4) ^ xr) * 8;                                 \
            short8 a0 = *(const short8*)(ApA + c8);                           \
            short8 a1 = *(const short8*)(ApA + 16 * 64 + c8);                 \
            short8 b0 = *(const short8*)(ApB + c8);                           \
            short8 b1 = *(const short8*)(ApB + 16 * 64 + c8);                 \
            acc00 = __builtin_amdgcn_mfma_f32_16x16x32_bf16(a0, b0, acc00, 0, 0, 0); \
            acc01 = __builtin_amdgcn_mfma_f32_16x16x32_bf16(a0, b1, acc01, 0, 0, 0); \
            acc10 = __builtin_amdgcn_mfma_f32_16x16x32_bf16(a1, b0, acc10, 0, 0, 0); \
            acc11 = __builtin_amdgcn_mfma_f32_16x16x32_bf16(a1, b1, acc11, 0, 0, 0); \
        }                                                                     \
        __syncthreads();                                                      \
    }                                                                         \
    int prow[4], pcol[4];                                                     \
    mfma_probe(lane, prow, pcol);                                             \
    _Pragma("unroll")                                                         \
    for (int r = 0; r < 4; r++) {                                             \
        cs[wm * 32 + prow[r]][wn * 32 + pcol[r]]           = acc00[r];        \
        cs[wm * 32 + prow[r]][wn * 32 + 16 + pcol[r]]      = acc01[r];        \
        cs[wm * 32 + 16 + prow[r]][wn * 32 + pcol[r]]      = acc10[r];        \
        cs[wm * 32 + 16 + prow[r]][wn * 32 + 16 + pcol[r]] = acc11[r];        \
    }                                                                         \
    __syncthreads();

// ---------------------------------------------------------------------------
// GEMM h: 64 nodes x 64 e (one head). Epilogue: bf16 hT [y][e][n] + src/dst.
// ---------------------------------------------------------------------------
__global__ __launch_bounds__(256) void gemm_h_kernel(const u16* __restrict__ featb,
                                                     const u16* __restrict__ Wt,
                                                     const float* __restrict__ wsrc,
                                                     const float* __restrict__ wdst,
                                                     u16* __restrict__ hT,
                                                     float* __restrict__ Sbuf,
                                                     float* __restrict__ Dbuf) {
    __shared__ u16 As[64 * 64];
    __shared__ u16 Bs[64 * 64];
    __shared__ alignas(16) float cs[64][68];
    int t = threadIdx.x, w = t >> 6, lane = t & 63, q = lane >> 4, x = lane & 15;
    int m0 = blockIdx.x * 64, a = blockIdx.y;

    GEMM_CORE(featb + (size_t)m0 * DIN, Wt + (size_t)a * EE * DIN)

    int b = m0 >> 9;
    int y = b * AH + a;
    int nbase = m0 & 511;

    {
        int e = t >> 2, ng = t & 3;
        u32* dst = (u32*)&hT[((size_t)y * EE + e) * NN + nbase + ng * 16];
#pragma unroll
        for (int i = 0; i < 8; i++)
            dst[i] = pk2(cs[ng * 16 + 2 * i][e], cs[ng * 16 + 2 * i + 1][e]);
    }
    {
        int r = t >> 2, cg = t & 3;
        float s = 0.f, d = 0.f;
#pragma unroll
        for (int i = 0; i < 16; i++) {
            int e2 = cg * 16 + i;
            float th = ftanh(cs[r][e2]);
            s += th * wsrc[a * EE + e2];
            d += th * wdst[a * EE + e2];
        }
        s += __shfl_xor(s, 1); s += __shfl_xor(s, 2);
        d += __shfl_xor(d, 1); d += __shfl_xor(d, 2);
        if (cg == 0) {
            Sbuf[y * NN + nbase + r] = s;
            Dbuf[y * NN + nbase + r] = d;
        }
    }
}

// ---------------------------------------------------------------------------
// GEMM gate + fused sigmoid/blend (epilogue verified).
// ---------------------------------------------------------------------------
static __device__ __forceinline__ float sigm(float z) {
    z = fminf(fmaxf(z, -80.f), 80.f);
    return 1.f / (1.f + __expf(-z));
}
__global__ __launch_bounds__(256) void gemm_gate_kernel(const u16* __restrict__ featb,
                                                        const u16* __restrict__ Hwb,
                                                        const float* __restrict__ Hb,
                                                        const float* __restrict__ feat,
                                                        float* __restrict__ out) {
    __shared__ u16 As[64 * 64];
    __shared__ u16 Bs[64 * 64];
    __shared__ alignas(16) float cs[64][68];
    int t = threadIdx.x, w = t >> 6, lane = t & 63, q = lane >> 4, x = lane & 15;
    int m0 = blockIdx.x * 64, n0 = blockIdx.y * 64;

    GEMM_CORE(featb + (size_t)m0 * DIN, Hwb + (size_t)n0 * DIN)

    float4 hb = *(const float4*)&Hb[n0 + (t & 15) * 4];
#pragma unroll
    for (int p = 0; p < 4; p++) {
        int ml = p * 16 + (t >> 4), c4 = (t & 15) * 4;
        float4 v4 = *(const float4*)&cs[ml][c4];
        size_t idx = (size_t)(m0 + ml) * DIN + n0 + c4;
        float4 fo = *(const float4*)&out[idx];
        float4 f4 = *(const float4*)&feat[idx];
        float4 o;
        float g;
        g = sigm(v4.x + hb.x); o.x = g * fo.x + (1.f - g) * f4.x;
        g = sigm(v4.y + hb.y); o.y = g * fo.y + (1.f - g) * f4.y;
        g = sigm(v4.z + hb.z); o.z = g * fo.z + (1.f - g) * f4.z;
        g = sigm(v4.w + hb.w); o.w = g * fo.w + (1.f - g) * f4.w;
        *(float4*)&out[idx] = o;
    }
}

// ---------------------------------------------------------------------------
// Attention: NO stats pass. Unnormalized p = exp(leaky(src+dst))*mask in the
// PV loop (bounded logits -> no overflow, clamp 60 for proof); row sum l
// accumulated on the fly (each lane covers 1/4 of its row; shfl_xor 16/32
// completes it); epilogue scales by 1/l. Uniform rows via mask-OR detect.
// ---------------------------------------------------------------------------
__global__ __launch_bounds__(256) void attn_kernel(const u16* __restrict__ hT,
                                                   const float* __restrict__ Sbuf,
                                                   const float* __restrict__ Dbuf,
                                                   const u32* __restrict__ maskbuf,
                                                   const float* __restrict__ bias,
                                                   float* __restrict__ out) {
    __shared__ alignas(16) float sdst[NN];
    __shared__ u32 smask[64][17];
    __shared__ float silv[64];
    __shared__ alignas(16) float cs[64][68];

    int t = threadIdx.x;
    int y = blockIdx.y, bb = y / AH, a = y % AH;
    int i0 = blockIdx.x * 64;

    sdst[t] = Dbuf[y * NN + t];
    sdst[t + 256] = Dbuf[y * NN + 256 + t];
#pragma unroll
    for (int p = 0; p < 4; p++) {
        int idx = p * 256 + t, r = idx >> 4, c = idx & 15;
        smask[r][c] = maskbuf[((bb << 9) + i0 + r) * 16 + c];
    }
    __syncthreads();

    int w = t >> 6, lane = t & 63, q = lane >> 4, x = lane & 15;
    int rowl = w * 16 + x;                      // A-convention row this lane supplies
    float srcv = Sbuf[y * NN + i0 + rowl];

    u32 anym = 0;
#pragma unroll
    for (int c = 0; c < 16; c++) anym |= smask[rowl][c];
    int uni = (anym == 0);

    const u16* hTy = hT + (size_t)y * EE * NN;
    f32x4 acc[4] = {};
    float lsum = 0.f;

#pragma unroll 2
    for (int k0 = 0; k0 < NN; k0 += 32) {
        u32 mb = smask[rowl][k0 >> 5] >> (q * 8);
        float pv[8];
#pragma unroll
        for (int j = 0; j < 8; j++) {
            float v = srcv + sdst[k0 + q * 8 + j];
            v = fmaxf(v, LEAKY * v);
            float e = __expf(fminf(v, 60.f));       // unnormalized, bounded
            float pm = ((mb >> j) & 1) ? e : 0.f;
            pv[j] = uni ? 1.0f : pm;
            lsum += pv[j];
        }
        short8 af;
        af[0] = (short)f2bf(pv[0]); af[1] = (short)f2bf(pv[1]);
        af[2] = (short)f2bf(pv[2]); af[3] = (short)f2bf(pv[3]);
        af[4] = (short)f2bf(pv[4]); af[5] = (short)f2bf(pv[5]);
        af[6] = (short)f2bf(pv[6]); af[7] = (short)f2bf(pv[7]);
        const u16* hp = hTy + (size_t)x * NN + k0 + q * 8;
        short8 b0 = *(const short8*)(hp);
        short8 b1 = *(const short8*)(hp + 16 * NN);
        short8 b2 = *(const short8*)(hp + 32 * NN);
        short8 b3 = *(const short8*)(hp + 48 * NN);
        acc[0] = __builtin_amdgcn_mfma_f32_16x16x32_bf16(af, b0, acc[0], 0, 0, 0);
        acc[1] = __builtin_amdgcn_mfma_f32_16x16x32_bf16(af, b1, acc[1], 0, 0, 0);
        acc[2] = __builtin_amdgcn_mfma_f32_16x16x32_bf16(af, b2, acc[2], 0, 0, 0);
        acc[3] = __builtin_amdgcn_mfma_f32_16x16x32_bf16(af, b3, acc[3], 0, 0, 0);
    }

    // complete row sum across the 4 quads holding this row
    lsum += __shfl_xor(lsum, 16);
    lsum += __shfl_xor(lsum, 32);
    if (q == 0) silv[rowl] = 1.f / fmaxf(lsum, 1e-30f);

    int prow[4], pcol[4];
    mfma_probe(lane, prow, pcol);
#pragma unroll
    for (int nt = 0; nt < 4; nt++)
#pragma unroll
        for (int r = 0; r < 4; r++)
            cs[w * 16 + prow[r]][nt * 16 + pcol[r]] = acc[nt][r];
    __syncthreads();

    float4 b4 = *(const float4*)&bias[(t & 15) * 4];
#pragma unroll
    for (int p = 0; p < 4; p++) {
        int nl = p * 16 + (t >> 4), e4 = (t & 15) * 4;
        float il = silv[nl];
        float4 c4 = *(const float4*)&cs[nl][e4];
        float4 o;
        float v;
        v = c4.x * il + b4.x; o.x = v > 0.f ? v : __expf(v) - 1.f;
        v = c4.y * il + b4.y; o.y = v > 0.f ? v : __expf(v) - 1.f;
        v = c4.z * il + b4.z; o.z = v > 0.f ? v : __expf(v) - 1.f;
        v = c4.w * il + b4.w; o.w = v > 0.f ? v : __expf(v) - 1.f;
        *(float4*)&out[((size_t)(bb << 9) + i0 + nl) * DIN + a * EE + e4] = o;
    }
}

// ---------------------------------------------------------------------------
extern "C" void kernel_launch(void* const* d_in, const int* in_sizes, int n_in,
                              void* d_out, int out_size, void* d_ws, size_t ws_size,
                              hipStream_t stream) {
    const float* feat  = (const float*)d_in[0];
    const int*   adj   = (const int*)  d_in[1];
    const float* W     = (const float*)d_in[2];
    const float* bvec  = (const float*)d_in[3];
    const float* wsrc  = (const float*)d_in[4];
    const float* wdst  = (const float*)d_in[5];
    const float* Hw    = (const float*)d_in[6];
    const float* Hb    = (const float*)d_in[7];
    float* out = (float*)d_out;

    char* ws = (char*)d_ws;
    u16*  featb   = (u16*)(ws);                       // 6,291,456 B
    u16*  Wt      = (u16*)(ws + 6291456);             // 1,179,648 B
    u16*  Hwb     = (u16*)(ws + 7471104);             // 1,179,648 B
    u16*  hT      = (u16*)(ws + 8650752);             // 6,291,456 B
    float* Sbuf   = (float*)(ws + 14942208);          //   196,608 B
    float* Dbuf   = (float*)(ws + 15138816);          //   196,608 B
    u32*  maskbuf = (u32*)(ws + 15335424);            //   262,144 B

    pack_adj_kernel<<<MM / 4, 256, 0, stream>>>(adj, maskbuf);
    convert_kernel<<<(N_FEAT + 2 * N_W) / 256, 256, 0, stream>>>(feat, W, Hw, featb, Wt, Hwb);
    gemm_h_kernel<<<dim3(MM / 64, AH), 256, 0, stream>>>(featb, Wt, wsrc, wdst, hT, Sbuf, Dbuf);
    attn_kernel<<<dim3(NN / 64, YY), 256, 0, stream>>>(hT, Sbuf, Dbuf, maskbuf, bvec, out);
    gemm_gate_kernel<<<dim3(MM / 64, DIN / 64), 256, 0, stream>>>(featb, Hwb, Hb, feat, out);
}

// Round 10
// 142.569 us; speedup vs baseline: 2.7227x; 1.0193x over previous
//
#include <hip/hip_runtime.h>
#include <hip/hip_bf16.h>

#define BB 8
#define NN 512
#define AH 12
#define DIN 768
#define EE 64
#define MM (BB*NN)          // 4096
#define YY (BB*AH)          // 96
#define LEAKY 0.2f

typedef unsigned short u16;
typedef unsigned int u32;
typedef __attribute__((ext_vector_type(8))) short short8;
typedef __attribute__((ext_vector_type(4))) float f32x4;
typedef __attribute__((ext_vector_type(4))) u32 u32x4;

// float -> bf16 RNE
static __device__ __forceinline__ u16 f2bf(float f) {
    u32 u = __builtin_bit_cast(u32, f);
    u32 r = (u + 0x7FFFu + ((u >> 16) & 1u)) >> 16;
    return (u16)r;
}
static __device__ __forceinline__ u32 pk2(float a, float b) {
    return (u32)f2bf(a) | ((u32)f2bf(b) << 16);
}
// truncation pack (p >= 0): 3 ops, rel err <= 2^-8 — used only for P
static __device__ __forceinline__ u32 pk2t(float a, float b) {
    return (__builtin_bit_cast(u32, a) >> 16) | (__builtin_bit_cast(u32, b) & 0xFFFF0000u);
}
static __device__ __forceinline__ float ftanh(float x) {
    x = fminf(fmaxf(x, -15.f), 15.f);
    return 1.f - 2.f / (__expf(2.f * x) + 1.f);
}
// async global->LDS, 16B per lane; LDS dest = wave-uniform base + lane*16
static __device__ __forceinline__ void gl_lds16(const u16* g, u16* l) {
    __builtin_amdgcn_global_load_lds((const __attribute__((address_space(1))) unsigned int*)g,
                                     (__attribute__((address_space(3))) unsigned int*)l,
                                     16, 0, 0);
}

// ---------------------------------------------------------------------------
// Hardware C/D-layout probe (validated rounds 6-9).
// ---------------------------------------------------------------------------
static __device__ __forceinline__ void mfma_probe(int lane, int* prow, int* pcol) {
    int q = lane >> 4, x = lane & 15;
    short8 af, bf;
#pragma unroll
    for (int j = 0; j < 8; j++) {
        int k = q * 8 + j;
        af[j] = (short)f2bf((k < 16) ? (float)(x * 16 + k) : 0.f);
        bf[j] = (short)f2bf((k == x) ? 1.f : 0.f);
    }
    f32x4 d = {};
    d = __builtin_amdgcn_mfma_f32_16x16x32_bf16(af, bf, d, 0, 0, 0);
#pragma unroll
    for (int r = 0; r < 4; r++) {
        int v = (int)(d[r] + 0.5f);
        prow[r] = v >> 4;
        pcol[r] = v & 15;
    }
}

// ---------------------------------------------------------------------------
// Pack adjacency rows into bitmasks (verified).
// ---------------------------------------------------------------------------
__global__ __launch_bounds__(256) void pack_adj_kernel(const int* __restrict__ adj,
                                                       u32* __restrict__ maskbuf) {
    int t = threadIdx.x, w = t >> 6, ln = t & 63;
    int row = blockIdx.x * 4 + w;
    const int* ar = adj + (size_t)row * NN;
#pragma unroll
    for (int it = 0; it < 8; it++) {
        unsigned long long bal = __ballot(ar[it * 64 + ln] != 0);
        if (ln == 0) {
            maskbuf[row * 16 + it * 2]     = (u32)bal;
            maskbuf[row * 16 + it * 2 + 1] = (u32)(bal >> 32);
        }
    }
}

// ---------------------------------------------------------------------------
// bf16 conversions (verified).
// ---------------------------------------------------------------------------
#define N_FEAT (MM*DIN)            // 3145728
#define N_W    (AH*DIN*EE)         // 589824
__global__ __launch_bounds__(256) void convert_kernel(const float* __restrict__ feat,
                                                      const float* __restrict__ W,
                                                      const float* __restrict__ Hw,
                                                      u16* __restrict__ featb,
                                                      u16* __restrict__ Wt,
                                                      u16* __restrict__ Hwb) {
    int i = blockIdx.x * 256 + threadIdx.x;
    if (i < N_FEAT) { featb[i] = f2bf(feat[i]); return; }
    int i2 = i - N_FEAT;
    if (i2 < N_W) {
        int a = i2 / (DIN * EE), rem = i2 % (DIN * EE);
        int e = rem / DIN, d = rem % DIN;
        Wt[i2] = f2bf(W[a * (DIN * EE) + d * EE + e]);
        return;
    }
    int i3 = i2 - N_W;
    Hwb[i3] = f2bf(Hw[i3]);
}

// ---------------------------------------------------------------------------
// K-loop core (verified round 9): 64x64 C tile, BK=64, global_load_lds
// staging, XOR k-swizzle, probe-indexed C->LDS.
// ---------------------------------------------------------------------------
#define GEMM_CORE(Abase, Bbase)                                               \
    int wm = w & 1, wn = w >> 1, xr = x & 7;                                  \
    int srow = t >> 3;                                                        \
    int skoff = ((t & 7) ^ (srow & 7)) * 8;                                   \
    const u16* Agp = (Abase) + srow * DIN + skoff;                            \
    const u16* Bgp = (Bbase) + srow * DIN + skoff;                            \
    u16* Asw = As + w * 512;                                                  \
    u16* Bsw = Bs + w * 512;                                                  \
    const u16* ApA = As + (wm * 32 + x) * 64;                                 \
    const u16* ApB = Bs + (wn * 32 + x) * 64;                                 \
    f32x4 acc00 = {}, acc01 = {}, acc10 = {}, acc11 = {};                     \
    for (int k0 = 0; k0 < DIN; k0 += 64) {                                    \
        gl_lds16(Agp + k0, Asw);                                              \
        gl_lds16(Agp + 32 * DIN + k0, Asw + 2048);                            \
        gl_lds16(Bgp + k0, Bsw);                                              \
        gl_lds16(Bgp + 32 * DIN + k0, Bsw + 2048);                            \
        __syncthreads();                                                      \
        _Pragma("unroll")                                                     \
        for (int kk = 0; kk < 2; kk++) {                                      \
            int c8 = ((q + kk * 4) ^ xr) * 8;                                 \
            short8 a0 = *(const short8*)(ApA + c8);                           \
            short8 a1 = *(const short8*)(ApA + 16 * 64 + c8);                 \
            short8 b0 = *(const short8*)(ApB + c8);                           \
            short8 b1 = *(const short8*)(ApB + 16 * 64 + c8);                 \
            acc00 = __builtin_amdgcn_mfma_f32_16x16x32_bf16(a0, b0, acc00, 0, 0, 0); \
            acc01 = __builtin_amdgcn_mfma_f32_16x16x32_bf16(a0, b1, acc01, 0, 0, 0); \
            acc10 = __builtin_amdgcn_mfma_f32_16x16x32_bf16(a1, b0, acc10, 0, 0, 0); \
            acc11 = __builtin_amdgcn_mfma_f32_16x16x32_bf16(a1, b1, acc11, 0, 0, 0); \
        }                                                                     \
        __syncthreads();                                                      \
    }                                                                         \
    int prow[4], pcol[4];                                                     \
    mfma_probe(lane, prow, pcol);                                             \
    _Pragma("unroll")                                                         \
    for (int r = 0; r < 4; r++) {                                             \
        cs[wm * 32 + prow[r]][wn * 32 + pcol[r]]           = acc00[r];        \
        cs[wm * 32 + prow[r]][wn * 32 + 16 + pcol[r]]      = acc01[r];        \
        cs[wm * 32 + 16 + prow[r]][wn * 32 + pcol[r]]      = acc10[r];        \
        cs[wm * 32 + 16 + prow[r]][wn * 32 + 16 + pcol[r]] = acc11[r];        \
    }                                                                         \
    __syncthreads();

// ---------------------------------------------------------------------------
// GEMM h: 64 nodes x 64 e (one head). Epilogue: bf16 hT [y][e][n] + factored
// exp pairs: Spair/Dpair[y][n] = {e^s, e^{0.2 s}} (clamped +-40).
// ---------------------------------------------------------------------------
__global__ __launch_bounds__(256) void gemm_h_kernel(const u16* __restrict__ featb,
                                                     const u16* __restrict__ Wt,
                                                     const float* __restrict__ wsrc,
                                                     const float* __restrict__ wdst,
                                                     u16* __restrict__ hT,
                                                     float2* __restrict__ Spair,
                                                     float2* __restrict__ Dpair) {
    __shared__ u16 As[64 * 64];
    __shared__ u16 Bs[64 * 64];
    __shared__ alignas(16) float cs[64][68];
    int t = threadIdx.x, w = t >> 6, lane = t & 63, q = lane >> 4, x = lane & 15;
    int m0 = blockIdx.x * 64, a = blockIdx.y;

    GEMM_CORE(featb + (size_t)m0 * DIN, Wt + (size_t)a * EE * DIN)

    int b = m0 >> 9;
    int y = b * AH + a;
    int nbase = m0 & 511;

    {
        int e = t >> 2, ng = t & 3;
        u32* dst = (u32*)&hT[((size_t)y * EE + e) * NN + nbase + ng * 16];
#pragma unroll
        for (int i = 0; i < 8; i++)
            dst[i] = pk2(cs[ng * 16 + 2 * i][e], cs[ng * 16 + 2 * i + 1][e]);
    }
    {
        int r = t >> 2, cg = t & 3;
        float s = 0.f, d = 0.f;
#pragma unroll
        for (int i = 0; i < 16; i++) {
            int e2 = cg * 16 + i;
            float th = ftanh(cs[r][e2]);
            s += th * wsrc[a * EE + e2];
            d += th * wdst[a * EE + e2];
        }
        s += __shfl_xor(s, 1); s += __shfl_xor(s, 2);
        d += __shfl_xor(d, 1); d += __shfl_xor(d, 2);
        if (cg == 0) {
            s = fminf(fmaxf(s, -40.f), 40.f);
            d = fminf(fmaxf(d, -40.f), 40.f);
            Spair[y * NN + nbase + r] = make_float2(__expf(s), __expf(0.2f * s));
            Dpair[y * NN + nbase + r] = make_float2(__expf(d), __expf(0.2f * d));
        }
    }
}

// ---------------------------------------------------------------------------
// GEMM gate (runs BEFORE attn): writes g = sigmoid(feat@HwT + Hb) to Gbuf.
// ---------------------------------------------------------------------------
static __device__ __forceinline__ float sigm(float z) {
    z = fminf(fmaxf(z, -80.f), 80.f);
    return 1.f / (1.f + __expf(-z));
}
__global__ __launch_bounds__(256) void gemm_gate_kernel(const u16* __restrict__ featb,
                                                        const u16* __restrict__ Hwb,
                                                        const float* __restrict__ Hb,
                                                        float* __restrict__ Gbuf) {
    __shared__ u16 As[64 * 64];
    __shared__ u16 Bs[64 * 64];
    __shared__ alignas(16) float cs[64][68];
    int t = threadIdx.x, w = t >> 6, lane = t & 63, q = lane >> 4, x = lane & 15;
    int m0 = blockIdx.x * 64, n0 = blockIdx.y * 64;

    GEMM_CORE(featb + (size_t)m0 * DIN, Hwb + (size_t)n0 * DIN)

    float4 hb = *(const float4*)&Hb[n0 + (t & 15) * 4];
#pragma unroll
    for (int p = 0; p < 4; p++) {
        int ml = p * 16 + (t >> 4), c4 = (t & 15) * 4;
        float4 v4 = *(const float4*)&cs[ml][c4];
        size_t idx = (size_t)(m0 + ml) * DIN + n0 + c4;
        float4 o;
        o.x = sigm(v4.x + hb.x);
        o.y = sigm(v4.y + hb.y);
        o.z = sigm(v4.z + hb.z);
        o.w = sigm(v4.w + hb.w);
        *(float4*)&Gbuf[idx] = o;
    }
}

// ---------------------------------------------------------------------------
// Attention: factored-exp PV (no transcendental in the hot loop), on-the-fly
// row sum, truncation bf16 pack, fused elu + gate blend epilogue.
//   p = (e^s e^d >= 1) ? e^s e^d : e^{.2s} e^{.2d}   [= exp(leaky(s+d))]
// ---------------------------------------------------------------------------
__global__ __launch_bounds__(256) void attn_kernel(const u16* __restrict__ hT,
                                                   const float2* __restrict__ Spair,
                                                   const float2* __restrict__ Dpair,
                                                   const u32* __restrict__ maskbuf,
                                                   const float* __restrict__ bias,
                                                   const float* __restrict__ Gbuf,
                                                   const float* __restrict__ feat,
                                                   float* __restrict__ out) {
    __shared__ alignas(16) float2 sd2[NN];
    __shared__ u32 smask[64][17];
    __shared__ float silv[64];
    __shared__ alignas(16) float cs[64][68];

    int t = threadIdx.x;
    int y = blockIdx.y, bb = y / AH, a = y % AH;
    int i0 = blockIdx.x * 64;

    sd2[t] = Dpair[y * NN + t];
    sd2[t + 256] = Dpair[y * NN + 256 + t];
#pragma unroll
    for (int p = 0; p < 4; p++) {
        int idx = p * 256 + t, r = idx >> 4, c = idx & 15;
        smask[r][c] = maskbuf[((bb << 9) + i0 + r) * 16 + c];
    }
    __syncthreads();

    int w = t >> 6, lane = t & 63, q = lane >> 4, x = lane & 15;
    int rowl = w * 16 + x;                      // A-convention row this lane supplies
    float2 se = Spair[y * NN + i0 + rowl];
    float es1 = se.x, es2 = se.y;

    u32 anym = 0;
#pragma unroll
    for (int c = 0; c < 16; c++) anym |= smask[rowl][c];
    int uni = (anym == 0);

    const u16* hTy = hT + (size_t)y * EE * NN;
    f32x4 acc[4] = {};
    float lsum = 0.f;

#pragma unroll 2
    for (int k0 = 0; k0 < NN; k0 += 32) {
        u32 mb = smask[rowl][k0 >> 5] >> (q * 8);
        float pv[8];
#pragma unroll
        for (int j = 0; j < 8; j++) {
            float2 dp = sd2[k0 + q * 8 + j];
            float m1 = es1 * dp.x;
            float m2 = es2 * dp.y;
            float p = (m1 >= 1.f) ? m1 : m2;    // exp(leaky(s+d)), no transcendental
            p = ((mb >> j) & 1) ? p : 0.f;
            p = uni ? 1.0f : p;
            lsum += p;
            pv[j] = p;
        }
        short8 af = __builtin_bit_cast(short8, (u32x4){
            pk2t(pv[0], pv[1]), pk2t(pv[2], pv[3]),
            pk2t(pv[4], pv[5]), pk2t(pv[6], pv[7])});
        const u16* hp = hTy + (size_t)x * NN + k0 + q * 8;
        short8 b0 = *(const short8*)(hp);
        short8 b1 = *(const short8*)(hp + 16 * NN);
        short8 b2 = *(const short8*)(hp + 32 * NN);
        short8 b3 = *(const short8*)(hp + 48 * NN);
        acc[0] = __builtin_amdgcn_mfma_f32_16x16x32_bf16(af, b0, acc[0], 0, 0, 0);
        acc[1] = __builtin_amdgcn_mfma_f32_16x16x32_bf16(af, b1, acc[1], 0, 0, 0);
        acc[2] = __builtin_amdgcn_mfma_f32_16x16x32_bf16(af, b2, acc[2], 0, 0, 0);
        acc[3] = __builtin_amdgcn_mfma_f32_16x16x32_bf16(af, b3, acc[3], 0, 0, 0);
    }

    // complete row sum across the 4 quads holding this row
    lsum += __shfl_xor(lsum, 16);
    lsum += __shfl_xor(lsum, 32);
    if (q == 0) silv[rowl] = 1.f / fmaxf(lsum, 1e-30f);

    int prow[4], pcol[4];
    mfma_probe(lane, prow, pcol);
#pragma unroll
    for (int nt = 0; nt < 4; nt++)
#pragma unroll
        for (int r = 0; r < 4; r++)
            cs[w * 16 + prow[r]][nt * 16 + pcol[r]] = acc[nt][r];
    __syncthreads();

    float4 b4 = *(const float4*)&bias[(t & 15) * 4];
#pragma unroll
    for (int p = 0; p < 4; p++) {
        int nl = p * 16 + (t >> 4), e4 = (t & 15) * 4;
        float il = silv[nl];
        float4 c4 = *(const float4*)&cs[nl][e4];
        size_t base = ((size_t)(bb << 9) + i0 + nl) * DIN + a * EE + e4;
        float4 g4 = *(const float4*)&Gbuf[base];
        float4 f4 = *(const float4*)&feat[base];
        float4 o;
        float v, e;
        v = c4.x * il + b4.x; e = v > 0.f ? v : __expf(v) - 1.f; o.x = g4.x * e + (1.f - g4.x) * f4.x;
        v = c4.y * il + b4.y; e = v > 0.f ? v : __expf(v) - 1.f; o.y = g4.y * e + (1.f - g4.y) * f4.y;
        v = c4.z * il + b4.z; e = v > 0.f ? v : __expf(v) - 1.f; o.z = g4.z * e + (1.f - g4.z) * f4.z;
        v = c4.w * il + b4.w; e = v > 0.f ? v : __expf(v) - 1.f; o.w = g4.w * e + (1.f - g4.w) * f4.w;
        *(float4*)&out[base] = o;
    }
}

// ---------------------------------------------------------------------------
extern "C" void kernel_launch(void* const* d_in, const int* in_sizes, int n_in,
                              void* d_out, int out_size, void* d_ws, size_t ws_size,
                              hipStream_t stream) {
    const float* feat  = (const float*)d_in[0];
    const int*   adj   = (const int*)  d_in[1];
    const float* W     = (const float*)d_in[2];
    const float* bvec  = (const float*)d_in[3];
    const float* wsrc  = (const float*)d_in[4];
    const float* wdst  = (const float*)d_in[5];
    const float* Hw    = (const float*)d_in[6];
    const float* Hb    = (const float*)d_in[7];
    float* out = (float*)d_out;

    char* ws = (char*)d_ws;
    u16*    featb   = (u16*)(ws);                       // 6,291,456 B
    u16*    Wt      = (u16*)(ws + 6291456);             // 1,179,648 B
    u16*    Hwb     = (u16*)(ws + 7471104);             // 1,179,648 B
    u16*    hT      = (u16*)(ws + 8650752);             // 6,291,456 B
    float2* Spair   = (float2*)(ws + 14942208);         //   393,216 B
    float2* Dpair   = (float2*)(ws + 15335424);         //   393,216 B
    u32*    maskbuf = (u32*)(ws + 15728640);            //   262,144 B
    float*  Gbuf    = (float*)(ws + 15990784);          // 12,582,912 B

    pack_adj_kernel<<<MM / 4, 256, 0, stream>>>(adj, maskbuf);
    convert_kernel<<<(N_FEAT + 2 * N_W) / 256, 256, 0, stream>>>(feat, W, Hw, featb, Wt, Hwb);
    gemm_h_kernel<<<dim3(MM / 64, AH), 256, 0, stream>>>(featb, Wt, wsrc, wdst, hT, Spair, Dpair);
    gemm_gate_kernel<<<dim3(MM / 64, DIN / 64), 256, 0, stream>>>(featb, Hwb, Hb, Gbuf);
    attn_kernel<<<dim3(NN / 64, YY), 256, 0, stream>>>(hT, Spair, Dpair, maskbuf, bvec, Gbuf, feat, out);
}

// Round 11
// 137.384 us; speedup vs baseline: 2.8255x; 1.0377x over previous
//
#include <hip/hip_runtime.h>
#include <hip/hip_bf16.h>

#define BB 8
#define NN 512
#define AH 12
#define DIN 768
#define EE 64
#define MM (BB*NN)          // 4096
#define YY (BB*AH)          // 96
#define LEAKY 0.2f

typedef unsigned short u16;
typedef unsigned int u32;
typedef __attribute__((ext_vector_type(8))) short short8;
typedef __attribute__((ext_vector_type(4))) float f32x4;
typedef __attribute__((ext_vector_type(4))) u32 u32x4;

// float -> bf16 RNE
static __device__ __forceinline__ u16 f2bf(float f) {
    u32 u = __builtin_bit_cast(u32, f);
    u32 r = (u + 0x7FFFu + ((u >> 16) & 1u)) >> 16;
    return (u16)r;
}
static __device__ __forceinline__ u32 pk2(float a, float b) {
    return (u32)f2bf(a) | ((u32)f2bf(b) << 16);
}
// truncation pack (p >= 0): used only for P (rel err <= 2^-8)
static __device__ __forceinline__ u32 pk2t(float a, float b) {
    return (__builtin_bit_cast(u32, a) >> 16) | (__builtin_bit_cast(u32, b) & 0xFFFF0000u);
}
static __device__ __forceinline__ float ftanh(float x) {
    x = fminf(fmaxf(x, -15.f), 15.f);
    return 1.f - 2.f / (__expf(2.f * x) + 1.f);
}
// async global->LDS, 16B per lane; LDS dest = wave-uniform base + lane*16
static __device__ __forceinline__ void gl_lds16(const u16* g, u16* l) {
    __builtin_amdgcn_global_load_lds((const __attribute__((address_space(1))) unsigned int*)g,
                                     (__attribute__((address_space(3))) unsigned int*)l,
                                     16, 0, 0);
}

// ---------------------------------------------------------------------------
// Hardware C/D-layout probe (validated rounds 6-10).
// ---------------------------------------------------------------------------
static __device__ __forceinline__ void mfma_probe(int lane, int* prow, int* pcol) {
    int q = lane >> 4, x = lane & 15;
    short8 af, bf;
#pragma unroll
    for (int j = 0; j < 8; j++) {
        int k = q * 8 + j;
        af[j] = (short)f2bf((k < 16) ? (float)(x * 16 + k) : 0.f);
        bf[j] = (short)f2bf((k == x) ? 1.f : 0.f);
    }
    f32x4 d = {};
    d = __builtin_amdgcn_mfma_f32_16x16x32_bf16(af, bf, d, 0, 0, 0);
#pragma unroll
    for (int r = 0; r < 4; r++) {
        int v = (int)(d[r] + 0.5f);
        prow[r] = v >> 4;
        pcol[r] = v & 15;
    }
}

// ---------------------------------------------------------------------------
// Prep: pack_adj (blocks 0..1023) + bf16 conversions (blocks 1024..).
// ---------------------------------------------------------------------------
#define N_FEAT (MM*DIN)            // 3145728
#define N_W    (AH*DIN*EE)         // 589824
#define PACK_BLOCKS (MM/4)         // 1024
#define CONV_BLOCKS ((N_FEAT + 2*N_W)/256)  // 16896
__global__ __launch_bounds__(256) void prep_kernel(const int* __restrict__ adj,
                                                   const float* __restrict__ feat,
                                                   const float* __restrict__ W,
                                                   const float* __restrict__ Hw,
                                                   u32* __restrict__ maskbuf,
                                                   u16* __restrict__ featb,
                                                   u16* __restrict__ Wt,
                                                   u16* __restrict__ Hwb) {
    int blk = blockIdx.x, t = threadIdx.x;
    if (blk < PACK_BLOCKS) {
        int w = t >> 6, ln = t & 63;
        int row = blk * 4 + w;
        const int* ar = adj + (size_t)row * NN;
#pragma unroll
        for (int it = 0; it < 8; it++) {
            unsigned long long bal = __ballot(ar[it * 64 + ln] != 0);
            if (ln == 0) {
                maskbuf[row * 16 + it * 2]     = (u32)bal;
                maskbuf[row * 16 + it * 2 + 1] = (u32)(bal >> 32);
            }
        }
        return;
    }
    int i = (blk - PACK_BLOCKS) * 256 + t;
    if (i < N_FEAT) { featb[i] = f2bf(feat[i]); return; }
    int i2 = i - N_FEAT;
    if (i2 < N_W) {
        int a = i2 / (DIN * EE), rem = i2 % (DIN * EE);
        int e = rem / DIN, d = rem % DIN;
        Wt[i2] = f2bf(W[a * (DIN * EE) + d * EE + e]);
        return;
    }
    int i3 = i2 - N_W;
    Hwb[i3] = f2bf(Hw[i3]);
}

// ---------------------------------------------------------------------------
// K-loop core (verified rounds 9-10): 64x64 C tile, BK=64, global_load_lds
// staging, XOR k-swizzle, probe-indexed C->LDS.
// ---------------------------------------------------------------------------
#define GEMM_CORE(Abase, Bbase)                                               \
    int wm = w & 1, wn = w >> 1, xr = x & 7;                                  \
    int srow = t >> 3;                                                        \
    int skoff = ((t & 7) ^ (srow & 7)) * 8;                                   \
    const u16* Agp = (Abase) + srow * DIN + skoff;                            \
    const u16* Bgp = (Bbase) + srow * DIN + skoff;                            \
    u16* Asw = As + w * 512;                                                  \
    u16* Bsw = Bs + w * 512;                                                  \
    const u16* ApA = As + (wm * 32 + x) * 64;                                 \
    const u16* ApB = Bs + (wn * 32 + x) * 64;                                 \
    f32x4 acc00 = {}, acc01 = {}, acc10 = {}, acc11 = {};                     \
    for (int k0 = 0; k0 < DIN; k0 += 64) {                                    \
        gl_lds16(Agp + k0, Asw);                                              \
        gl_lds16(Agp + 32 * DIN + k0, Asw + 2048);                            \
        gl_lds16(Bgp + k0, Bsw);                                              \
        gl_lds16(Bgp + 32 * DIN + k0, Bsw + 2048);                            \
        __syncthreads();                                                      \
        _Pragma("unroll")                                                     \
        for (int kk = 0; kk < 2; kk++) {                                      \
            int c8 = ((q + kk * 4) ^ xr) * 8;                                 \
            short8 a0 = *(const short8*)(ApA + c8);                           \
            short8 a1 = *(const short8*)(ApA + 16 * 64 + c8);                 \
            short8 b0 = *(const short8*)(ApB + c8);                           \
            short8 b1 = *(const short8*)(ApB + 16 * 64 + c8);                 \
            acc00 = __builtin_amdgcn_mfma_f32_16x16x32_bf16(a0, b0, acc00, 0, 0, 0); \
            acc01 = __builtin_amdgcn_mfma_f32_16x16x32_bf16(a0, b1, acc01, 0, 0, 0); \
            acc10 = __builtin_amdgcn_mfma_f32_16x16x32_bf16(a1, b0, acc10, 0, 0, 0); \
            acc11 = __builtin_amdgcn_mfma_f32_16x16x32_bf16(a1, b1, acc11, 0, 0, 0); \
        }                                                                     \
        __syncthreads();                                                      \
    }                                                                         \
    int prow[4], pcol[4];                                                     \
    mfma_probe(lane, prow, pcol);                                             \
    _Pragma("unroll")                                                         \
    for (int r = 0; r < 4; r++) {                                             \
        cs[wm * 32 + prow[r]][wn * 32 + pcol[r]]           = acc00[r];        \
        cs[wm * 32 + prow[r]][wn * 32 + 16 + pcol[r]]      = acc01[r];        \
        cs[wm * 32 + 16 + prow[r]][wn * 32 + pcol[r]]      = acc10[r];        \
        cs[wm * 32 + 16 + prow[r]][wn * 32 + 16 + pcol[r]] = acc11[r];        \
    }                                                                         \
    __syncthreads();

static __device__ __forceinline__ float sigm(float z) {
    z = fminf(fmaxf(z, -80.f), 80.f);
    return 1.f / (1.f + __expf(-z));
}

// ---------------------------------------------------------------------------
// Fused GEMM: grid (64 m-tiles, 24). y<12: h-GEMM head y (epilogue: bf16 hT
// + factored exp pairs). y>=12: gate GEMM n-tile y-12 (epilogue: sigmoid).
// One launch -> 1536 resident blocks (~6/CU) for latency hiding.
// ---------------------------------------------------------------------------
__global__ __launch_bounds__(256) void gemm_fused_kernel(const u16* __restrict__ featb,
                                                         const u16* __restrict__ Wt,
                                                         const u16* __restrict__ Hwb,
                                                         const float* __restrict__ wsrc,
                                                         const float* __restrict__ wdst,
                                                         const float* __restrict__ Hb,
                                                         u16* __restrict__ hT,
                                                         float2* __restrict__ Spair,
                                                         float2* __restrict__ Dpair,
                                                         float* __restrict__ Gbuf) {
    __shared__ u16 As[64 * 64];
    __shared__ u16 Bs[64 * 64];
    __shared__ alignas(16) float cs[64][68];
    int t = threadIdx.x, w = t >> 6, lane = t & 63, q = lane >> 4, x = lane & 15;
    int m0 = blockIdx.x * 64;
    int yb = blockIdx.y;

    if (yb < AH) {
        int a = yb;
        GEMM_CORE(featb + (size_t)m0 * DIN, Wt + (size_t)a * EE * DIN)

        int b = m0 >> 9;
        int y = b * AH + a;
        int nbase = m0 & 511;
        {
            int e = t >> 2, ng = t & 3;
            u32* dst = (u32*)&hT[((size_t)y * EE + e) * NN + nbase + ng * 16];
#pragma unroll
            for (int i = 0; i < 8; i++)
                dst[i] = pk2(cs[ng * 16 + 2 * i][e], cs[ng * 16 + 2 * i + 1][e]);
        }
        {
            int r = t >> 2, cg = t & 3;
            float s = 0.f, d = 0.f;
#pragma unroll
            for (int i = 0; i < 16; i++) {
                int e2 = cg * 16 + i;
                float th = ftanh(cs[r][e2]);
                s += th * wsrc[a * EE + e2];
                d += th * wdst[a * EE + e2];
            }
            s += __shfl_xor(s, 1); s += __shfl_xor(s, 2);
            d += __shfl_xor(d, 1); d += __shfl_xor(d, 2);
            if (cg == 0) {
                s = fminf(fmaxf(s, -40.f), 40.f);
                d = fminf(fmaxf(d, -40.f), 40.f);
                Spair[y * NN + nbase + r] = make_float2(__expf(s), __expf(0.2f * s));
                Dpair[y * NN + nbase + r] = make_float2(__expf(d), __expf(0.2f * d));
            }
        }
    } else {
        int n0 = (yb - AH) * 64;
        GEMM_CORE(featb + (size_t)m0 * DIN, Hwb + (size_t)n0 * DIN)

        float4 hb = *(const float4*)&Hb[n0 + (t & 15) * 4];
#pragma unroll
        for (int p = 0; p < 4; p++) {
            int ml = p * 16 + (t >> 4), c4 = (t & 15) * 4;
            float4 v4 = *(const float4*)&cs[ml][c4];
            size_t idx = (size_t)(m0 + ml) * DIN + n0 + c4;
            float4 o;
            o.x = sigm(v4.x + hb.x);
            o.y = sigm(v4.y + hb.y);
            o.z = sigm(v4.z + hb.z);
            o.w = sigm(v4.w + hb.w);
            *(float4*)&Gbuf[idx] = o;
        }
    }
}

// ---------------------------------------------------------------------------
// Attention (verified round 10): factored-exp PV, on-the-fly row sum,
// truncation bf16 pack, fused elu + gate blend epilogue.
// ---------------------------------------------------------------------------
__global__ __launch_bounds__(256) void attn_kernel(const u16* __restrict__ hT,
                                                   const float2* __restrict__ Spair,
                                                   const float2* __restrict__ Dpair,
                                                   const u32* __restrict__ maskbuf,
                                                   const float* __restrict__ bias,
                                                   const float* __restrict__ Gbuf,
                                                   const float* __restrict__ feat,
                                                   float* __restrict__ out) {
    __shared__ alignas(16) float2 sd2[NN];
    __shared__ u32 smask[64][17];
    __shared__ float silv[64];
    __shared__ alignas(16) float cs[64][68];

    int t = threadIdx.x;
    int y = blockIdx.y, bb = y / AH, a = y % AH;
    int i0 = blockIdx.x * 64;

    sd2[t] = Dpair[y * NN + t];
    sd2[t + 256] = Dpair[y * NN + 256 + t];
#pragma unroll
    for (int p = 0; p < 4; p++) {
        int idx = p * 256 + t, r = idx >> 4, c = idx & 15;
        smask[r][c] = maskbuf[((bb << 9) + i0 + r) * 16 + c];
    }
    __syncthreads();

    int w = t >> 6, lane = t & 63, q = lane >> 4, x = lane & 15;
    int rowl = w * 16 + x;
    float2 se = Spair[y * NN + i0 + rowl];
    float es1 = se.x, es2 = se.y;

    u32 anym = 0;
#pragma unroll
    for (int c = 0; c < 16; c++) anym |= smask[rowl][c];
    int uni = (anym == 0);

    const u16* hTy = hT + (size_t)y * EE * NN;
    f32x4 acc[4] = {};
    float lsum = 0.f;

#pragma unroll 2
    for (int k0 = 0; k0 < NN; k0 += 32) {
        u32 mb = smask[rowl][k0 >> 5] >> (q * 8);
        float pv[8];
#pragma unroll
        for (int j = 0; j < 8; j++) {
            float2 dp = sd2[k0 + q * 8 + j];
            float m1 = es1 * dp.x;
            float m2 = es2 * dp.y;
            float p = (m1 >= 1.f) ? m1 : m2;
            p = ((mb >> j) & 1) ? p : 0.f;
            p = uni ? 1.0f : p;
            lsum += p;
            pv[j] = p;
        }
        short8 af = __builtin_bit_cast(short8, (u32x4){
            pk2t(pv[0], pv[1]), pk2t(pv[2], pv[3]),
            pk2t(pv[4], pv[5]), pk2t(pv[6], pv[7])});
        const u16* hp = hTy + (size_t)x * NN + k0 + q * 8;
        short8 b0 = *(const short8*)(hp);
        short8 b1 = *(const short8*)(hp + 16 * NN);
        short8 b2 = *(const short8*)(hp + 32 * NN);
        short8 b3 = *(const short8*)(hp + 48 * NN);
        acc[0] = __builtin_amdgcn_mfma_f32_16x16x32_bf16(af, b0, acc[0], 0, 0, 0);
        acc[1] = __builtin_amdgcn_mfma_f32_16x16x32_bf16(af, b1, acc[1], 0, 0, 0);
        acc[2] = __builtin_amdgcn_mfma_f32_16x16x32_bf16(af, b2, acc[2], 0, 0, 0);
        acc[3] = __builtin_amdgcn_mfma_f32_16x16x32_bf16(af, b3, acc[3], 0, 0, 0);
    }

    lsum += __shfl_xor(lsum, 16);
    lsum += __shfl_xor(lsum, 32);
    if (q == 0) silv[rowl] = 1.f / fmaxf(lsum, 1e-30f);

    int prow[4], pcol[4];
    mfma_probe(lane, prow, pcol);
#pragma unroll
    for (int nt = 0; nt < 4; nt++)
#pragma unroll
        for (int r = 0; r < 4; r++)
            cs[w * 16 + prow[r]][nt * 16 + pcol[r]] = acc[nt][r];
    __syncthreads();

    float4 b4 = *(const float4*)&bias[(t & 15) * 4];
#pragma unroll
    for (int p = 0; p < 4; p++) {
        int nl = p * 16 + (t >> 4), e4 = (t & 15) * 4;
        float il = silv[nl];
        float4 c4 = *(const float4*)&cs[nl][e4];
        size_t base = ((size_t)(bb << 9) + i0 + nl) * DIN + a * EE + e4;
        float4 g4 = *(const float4*)&Gbuf[base];
        float4 f4 = *(const float4*)&feat[base];
        float4 o;
        float v, e;
        v = c4.x * il + b4.x; e = v > 0.f ? v : __expf(v) - 1.f; o.x = g4.x * e + (1.f - g4.x) * f4.x;
        v = c4.y * il + b4.y; e = v > 0.f ? v : __expf(v) - 1.f; o.y = g4.y * e + (1.f - g4.y) * f4.y;
        v = c4.z * il + b4.z; e = v > 0.f ? v : __expf(v) - 1.f; o.z = g4.z * e + (1.f - g4.z) * f4.z;
        v = c4.w * il + b4.w; e = v > 0.f ? v : __expf(v) - 1.f; o.w = g4.w * e + (1.f - g4.w) * f4.w;
        *(float4*)&out[base] = o;
    }
}

// ---------------------------------------------------------------------------
extern "C" void kernel_launch(void* const* d_in, const int* in_sizes, int n_in,
                              void* d_out, int out_size, void* d_ws, size_t ws_size,
                              hipStream_t stream) {
    const float* feat  = (const float*)d_in[0];
    const int*   adj   = (const int*)  d_in[1];
    const float* W     = (const float*)d_in[2];
    const float* bvec  = (const float*)d_in[3];
    const float* wsrc  = (const float*)d_in[4];
    const float* wdst  = (const float*)d_in[5];
    const float* Hw    = (const float*)d_in[6];
    const float* Hb    = (const float*)d_in[7];
    float* out = (float*)d_out;

    char* ws = (char*)d_ws;
    u16*    featb   = (u16*)(ws);                       // 6,291,456 B
    u16*    Wt      = (u16*)(ws + 6291456);             // 1,179,648 B
    u16*    Hwb     = (u16*)(ws + 7471104);             // 1,179,648 B
    u16*    hT      = (u16*)(ws + 8650752);             // 6,291,456 B
    float2* Spair   = (float2*)(ws + 14942208);         //   393,216 B
    float2* Dpair   = (float2*)(ws + 15335424);         //   393,216 B
    u32*    maskbuf = (u32*)(ws + 15728640);            //   262,144 B
    float*  Gbuf    = (float*)(ws + 15990784);          // 12,582,912 B

    prep_kernel<<<PACK_BLOCKS + CONV_BLOCKS, 256, 0, stream>>>(
        adj, feat, W, Hw, maskbuf, featb, Wt, Hwb);
    gemm_fused_kernel<<<dim3(MM / 64, 2 * AH), 256, 0, stream>>>(
        featb, Wt, Hwb, wsrc, wdst, Hb, hT, Spair, Dpair, Gbuf);
    attn_kernel<<<dim3(NN / 64, YY), 256, 0, stream>>>(
        hT, Spair, Dpair, maskbuf, bvec, Gbuf, feat, out);
}

// Round 12
// 136.145 us; speedup vs baseline: 2.8512x; 1.0091x over previous
//
#include <hip/hip_runtime.h>
#include <hip/hip_bf16.h>

#define BB 8
#define NN 512
#define AH 12
#define DIN 768
#define EE 64
#define MM (BB*NN)          // 4096
#define YY (BB*AH)          // 96
#define LEAKY 0.2f

typedef unsigned short u16;
typedef unsigned int u32;
typedef __attribute__((ext_vector_type(8))) short short8;
typedef __attribute__((ext_vector_type(4))) float f32x4;
typedef __attribute__((ext_vector_type(4))) u32 u32x4;

// float -> bf16 RNE
static __device__ __forceinline__ u16 f2bf(float f) {
    u32 u = __builtin_bit_cast(u32, f);
    u32 r = (u + 0x7FFFu + ((u >> 16) & 1u)) >> 16;
    return (u16)r;
}
static __device__ __forceinline__ u32 pk2(float a, float b) {
    return (u32)f2bf(a) | ((u32)f2bf(b) << 16);
}
// truncation pack (p >= 0): used only for P (rel err <= 2^-8)
static __device__ __forceinline__ u32 pk2t(float a, float b) {
    return (__builtin_bit_cast(u32, a) >> 16) | (__builtin_bit_cast(u32, b) & 0xFFFF0000u);
}
static __device__ __forceinline__ float ftanh(float x) {
    x = fminf(fmaxf(x, -15.f), 15.f);
    return 1.f - 2.f / (__expf(2.f * x) + 1.f);
}
static __device__ __forceinline__ float sigm(float z) {
    z = fminf(fmaxf(z, -80.f), 80.f);
    return 1.f / (1.f + __expf(-z));
}
// async global->LDS, 16B per lane
static __device__ __forceinline__ void gl_lds16(const u16* g, u16* l) {
    __builtin_amdgcn_global_load_lds((const __attribute__((address_space(1))) unsigned int*)g,
                                     (__attribute__((address_space(3))) unsigned int*)l,
                                     16, 0, 0);
}

// ---------------------------------------------------------------------------
// Hardware C/D-layout probe (validated rounds 6-11).
// ---------------------------------------------------------------------------
static __device__ __forceinline__ void mfma_probe(int lane, int* prow, int* pcol) {
    int q = lane >> 4, x = lane & 15;
    short8 af, bf;
#pragma unroll
    for (int j = 0; j < 8; j++) {
        int k = q * 8 + j;
        af[j] = (short)f2bf((k < 16) ? (float)(x * 16 + k) : 0.f);
        bf[j] = (short)f2bf((k == x) ? 1.f : 0.f);
    }
    f32x4 d = {};
    d = __builtin_amdgcn_mfma_f32_16x16x32_bf16(af, bf, d, 0, 0, 0);
#pragma unroll
    for (int r = 0; r < 4; r++) {
        int v = (int)(d[r] + 0.5f);
        prow[r] = v >> 4;
        pcol[r] = v & 15;
    }
}

// ---------------------------------------------------------------------------
// Prep: pack_adj (blocks 0..1023) + bf16 conversions (verified).
// ---------------------------------------------------------------------------
#define N_FEAT (MM*DIN)            // 3145728
#define N_W    (AH*DIN*EE)         // 589824
#define PACK_BLOCKS (MM/4)         // 1024
#define CONV_BLOCKS ((N_FEAT + 2*N_W)/256)  // 16896
__global__ __launch_bounds__(256) void prep_kernel(const int* __restrict__ adj,
                                                   const float* __restrict__ feat,
                                                   const float* __restrict__ W,
                                                   const float* __restrict__ Hw,
                                                   u32* __restrict__ maskbuf,
                                                   u16* __restrict__ featb,
                                                   u16* __restrict__ Wt,
                                                   u16* __restrict__ Hwb) {
    int blk = blockIdx.x, t = threadIdx.x;
    if (blk < PACK_BLOCKS) {
        int w = t >> 6, ln = t & 63;
        int row = blk * 4 + w;
        const int* ar = adj + (size_t)row * NN;
#pragma unroll
        for (int it = 0; it < 8; it++) {
            unsigned long long bal = __ballot(ar[it * 64 + ln] != 0);
            if (ln == 0) {
                maskbuf[row * 16 + it * 2]     = (u32)bal;
                maskbuf[row * 16 + it * 2 + 1] = (u32)(bal >> 32);
            }
        }
        return;
    }
    int i = (blk - PACK_BLOCKS) * 256 + t;
    if (i < N_FEAT) { featb[i] = f2bf(feat[i]); return; }
    int i2 = i - N_FEAT;
    if (i2 < N_W) {
        int a = i2 / (DIN * EE), rem = i2 % (DIN * EE);
        int e = rem / DIN, d = rem % DIN;
        Wt[i2] = f2bf(W[a * (DIN * EE) + d * EE + e]);
        return;
    }
    int i3 = i2 - N_W;
    Hwb[i3] = f2bf(Hw[i3]);
}

// ---------------------------------------------------------------------------
// K-loop core (verified rounds 9-11): 64x64 C tile, BK=64, global_load_lds
// staging, XOR k-swizzle, probe-indexed C->LDS. Ends with __syncthreads.
// ---------------------------------------------------------------------------
#define GEMM_CORE(Abase, Bbase)                                               \
    int wm = w & 1, wn = w >> 1, xr = x & 7;                                  \
    int srow = t >> 3;                                                        \
    int skoff = ((t & 7) ^ (srow & 7)) * 8;                                   \
    const u16* Agp = (Abase) + srow * DIN + skoff;                            \
    const u16* Bgp = (Bbase) + srow * DIN + skoff;                            \
    u16* Asw = As + w * 512;                                                  \
    u16* Bsw = Bs + w * 512;                                                  \
    const u16* ApA = As + (wm * 32 + x) * 64;                                 \
    const u16* ApB = Bs + (wn * 32 + x) * 64;                                 \
    f32x4 acc00 = {}, acc01 = {}, acc10 = {}, acc11 = {};                     \
    for (int k0 = 0; k0 < DIN; k0 += 64) {                                    \
        gl_lds16(Agp + k0, Asw);                                              \
        gl_lds16(Agp + 32 * DIN + k0, Asw + 2048);                            \
        gl_lds16(Bgp + k0, Bsw);                                              \
        gl_lds16(Bgp + 32 * DIN + k0, Bsw + 2048);                            \
        __syncthreads();                                                      \
        _Pragma("unroll")                                                     \
        for (int kk = 0; kk < 2; kk++) {                                      \
            int c8 = ((q + kk * 4) ^ xr) * 8;                                 \
            short8 a0 = *(const short8*)(ApA + c8);                           \
            short8 a1 = *(const short8*)(ApA + 16 * 64 + c8);                 \
            short8 b0 = *(const short8*)(ApB + c8);                           \
            short8 b1 = *(const short8*)(ApB + 16 * 64 + c8);                 \
            acc00 = __builtin_amdgcn_mfma_f32_16x16x32_bf16(a0, b0, acc00, 0, 0, 0); \
            acc01 = __builtin_amdgcn_mfma_f32_16x16x32_bf16(a0, b1, acc01, 0, 0, 0); \
            acc10 = __builtin_amdgcn_mfma_f32_16x16x32_bf16(a1, b0, acc10, 0, 0, 0); \
            acc11 = __builtin_amdgcn_mfma_f32_16x16x32_bf16(a1, b1, acc11, 0, 0, 0); \
        }                                                                     \
        __syncthreads();                                                      \
    }                                                                         \
    int prow[4], pcol[4];                                                     \
    mfma_probe(lane, prow, pcol);                                             \
    _Pragma("unroll")                                                         \
    for (int r = 0; r < 4; r++) {                                             \
        cs[wm * 32 + prow[r]][wn * 32 + pcol[r]]           = acc00[r];        \
        cs[wm * 32 + prow[r]][wn * 32 + 16 + pcol[r]]      = acc01[r];        \
        cs[wm * 32 + 16 + prow[r]][wn * 32 + pcol[r]]      = acc10[r];        \
        cs[wm * 32 + 16 + prow[r]][wn * 32 + 16 + pcol[r]] = acc11[r];        \
    }                                                                         \
    __syncthreads();

// ---------------------------------------------------------------------------
// GEMM h: 64 nodes x 64 e (one head). Epilogue: bf16 hT [y][e][n] + factored
// exp pairs (verified).
// ---------------------------------------------------------------------------
__global__ __launch_bounds__(256) void gemm_h_kernel(const u16* __restrict__ featb,
                                                     const u16* __restrict__ Wt,
                                                     const float* __restrict__ wsrc,
                                                     const float* __restrict__ wdst,
                                                     u16* __restrict__ hT,
                                                     float2* __restrict__ Spair,
                                                     float2* __restrict__ Dpair) {
    __shared__ u16 As[64 * 64];
    __shared__ u16 Bs[64 * 64];
    __shared__ alignas(16) float cs[64][68];
    int t = threadIdx.x, w = t >> 6, lane = t & 63, q = lane >> 4, x = lane & 15;
    int m0 = blockIdx.x * 64, a = blockIdx.y;

    GEMM_CORE(featb + (size_t)m0 * DIN, Wt + (size_t)a * EE * DIN)

    int b = m0 >> 9;
    int y = b * AH + a;
    int nbase = m0 & 511;
    {
        int e = t >> 2, ng = t & 3;
        u32* dst = (u32*)&hT[((size_t)y * EE + e) * NN + nbase + ng * 16];
#pragma unroll
        for (int i = 0; i < 8; i++)
            dst[i] = pk2(cs[ng * 16 + 2 * i][e], cs[ng * 16 + 2 * i + 1][e]);
    }
    {
        int r = t >> 2, cg = t & 3;
        float s = 0.f, d = 0.f;
#pragma unroll
        for (int i = 0; i < 16; i++) {
            int e2 = cg * 16 + i;
            float th = ftanh(cs[r][e2]);
            s += th * wsrc[a * EE + e2];
            d += th * wdst[a * EE + e2];
        }
        s += __shfl_xor(s, 1); s += __shfl_xor(s, 2);
        d += __shfl_xor(d, 1); d += __shfl_xor(d, 2);
        if (cg == 0) {
            s = fminf(fmaxf(s, -40.f), 40.f);
            d = fminf(fmaxf(d, -40.f), 40.f);
            Spair[y * NN + nbase + r] = make_float2(__expf(s), __expf(0.2f * s));
            Dpair[y * NN + nbase + r] = make_float2(__expf(d), __expf(0.2f * d));
        }
    }
}

// ---------------------------------------------------------------------------
// Attention + fused gate GEMM. Phase 1: gate 64x64 tile via GEMM_CORE
// (rows (bb*512+i0).., cols a*64..), sigmoid -> 16 VGPRs. Phase 2: PV via
// MFMA with factored-exp P (verified). LDS union: staging region (As/Bs)
// is dead by PV time and aliases sd2/smask.
// ---------------------------------------------------------------------------
__global__ __launch_bounds__(256) void attn_kernel(const u16* __restrict__ hT,
                                                   const float2* __restrict__ Spair,
                                                   const float2* __restrict__ Dpair,
                                                   const u32* __restrict__ maskbuf,
                                                   const float* __restrict__ bias,
                                                   const u16* __restrict__ featb,
                                                   const u16* __restrict__ Hwb,
                                                   const float* __restrict__ Hb,
                                                   const float* __restrict__ feat,
                                                   float* __restrict__ out) {
    __shared__ union {
        u16 stage[2][64 * 64];                       // As/Bs during gate GEMM
        struct {
            float2 sd2[NN];                          // 4 KB
            u32 smask[64][17];                       // 4.35 KB
        } pv;
    } ushr;
    __shared__ alignas(16) float cs[64][68];
    __shared__ float silv[64];

    int t = threadIdx.x;
    int y = blockIdx.y, bb = y / AH, a = y % AH;
    int i0 = blockIdx.x * 64;
    int w = t >> 6, lane = t & 63, q = lane >> 4, x = lane & 15;

    // ---- phase 1: gate GEMM tile -> sigmoid in registers ----
    float4 g4[4];
    {
        u16* As = ushr.stage[0];
        u16* Bs = ushr.stage[1];
        GEMM_CORE(featb + ((size_t)(bb << 9) + i0) * DIN, Hwb + (size_t)(a * EE) * DIN)
        float4 hb = *(const float4*)&Hb[a * EE + (t & 15) * 4];
#pragma unroll
        for (int p = 0; p < 4; p++) {
            int ml = p * 16 + (t >> 4), c4 = (t & 15) * 4;
            float4 v4 = *(const float4*)&cs[ml][c4];
            g4[p].x = sigm(v4.x + hb.x);
            g4[p].y = sigm(v4.y + hb.y);
            g4[p].z = sigm(v4.z + hb.z);
            g4[p].w = sigm(v4.w + hb.w);
        }
    }

    // ---- load PV working set (overwrites the staging region; the K-loop's
    //      final __syncthreads ordered all As/Bs reads before this) ----
    float2* sd2 = ushr.pv.sd2;
    u32 (*smask)[17] = ushr.pv.smask;
    sd2[t] = Dpair[y * NN + t];
    sd2[t + 256] = Dpair[y * NN + 256 + t];
#pragma unroll
    for (int p = 0; p < 4; p++) {
        int idx = p * 256 + t, r = idx >> 4, c = idx & 15;
        smask[r][c] = maskbuf[((bb << 9) + i0 + r) * 16 + c];
    }
    __syncthreads();   // sd2/smask visible; g4 cs-reads complete before PV overwrites cs

    // ---- phase 2: PV via MFMA (factored exp, on-the-fly row sum) ----
    int rowl = w * 16 + x;
    float2 se = Spair[y * NN + i0 + rowl];
    float es1 = se.x, es2 = se.y;

    u32 anym = 0;
#pragma unroll
    for (int c = 0; c < 16; c++) anym |= smask[rowl][c];
    int uni = (anym == 0);

    const u16* hTy = hT + (size_t)y * EE * NN;
    f32x4 acc[4] = {};
    float lsum = 0.f;

#pragma unroll 2
    for (int k0 = 0; k0 < NN; k0 += 32) {
        u32 mb = smask[rowl][k0 >> 5] >> (q * 8);
        float pv[8];
#pragma unroll
        for (int j = 0; j < 8; j++) {
            float2 dp = sd2[k0 + q * 8 + j];
            float m1 = es1 * dp.x;
            float m2 = es2 * dp.y;
            float p = (m1 >= 1.f) ? m1 : m2;    // exp(leaky(s+d))
            p = ((mb >> j) & 1) ? p : 0.f;
            p = uni ? 1.0f : p;
            lsum += p;
            pv[j] = p;
        }
        short8 af = __builtin_bit_cast(short8, (u32x4){
            pk2t(pv[0], pv[1]), pk2t(pv[2], pv[3]),
            pk2t(pv[4], pv[5]), pk2t(pv[6], pv[7])});
        const u16* hp = hTy + (size_t)x * NN + k0 + q * 8;
        short8 b0 = *(const short8*)(hp);
        short8 b1 = *(const short8*)(hp + 16 * NN);
        short8 b2 = *(const short8*)(hp + 32 * NN);
        short8 b3 = *(const short8*)(hp + 48 * NN);
        acc[0] = __builtin_amdgcn_mfma_f32_16x16x32_bf16(af, b0, acc[0], 0, 0, 0);
        acc[1] = __builtin_amdgcn_mfma_f32_16x16x32_bf16(af, b1, acc[1], 0, 0, 0);
        acc[2] = __builtin_amdgcn_mfma_f32_16x16x32_bf16(af, b2, acc[2], 0, 0, 0);
        acc[3] = __builtin_amdgcn_mfma_f32_16x16x32_bf16(af, b3, acc[3], 0, 0, 0);
    }

    lsum += __shfl_xor(lsum, 16);
    lsum += __shfl_xor(lsum, 32);
    if (q == 0) silv[rowl] = 1.f / fmaxf(lsum, 1e-30f);

    int prow[4], pcol[4];
    mfma_probe(lane, prow, pcol);
#pragma unroll
    for (int nt = 0; nt < 4; nt++)
#pragma unroll
        for (int r = 0; r < 4; r++)
            cs[w * 16 + prow[r]][nt * 16 + pcol[r]] = acc[nt][r];
    __syncthreads();

    // ---- epilogue: normalize, +bias, elu, gate blend (g4 from phase 1) ----
    float4 b4 = *(const float4*)&bias[(t & 15) * 4];
#pragma unroll
    for (int p = 0; p < 4; p++) {
        int nl = p * 16 + (t >> 4), e4 = (t & 15) * 4;
        float il = silv[nl];
        float4 c4 = *(const float4*)&cs[nl][e4];
        size_t base = ((size_t)(bb << 9) + i0 + nl) * DIN + a * EE + e4;
        float4 f4 = *(const float4*)&feat[base];
        float4 g = g4[p];
        float4 o;
        float v, e;
        v = c4.x * il + b4.x; e = v > 0.f ? v : __expf(v) - 1.f; o.x = g.x * e + (1.f - g.x) * f4.x;
        v = c4.y * il + b4.y; e = v > 0.f ? v : __expf(v) - 1.f; o.y = g.y * e + (1.f - g.y) * f4.y;
        v = c4.z * il + b4.z; e = v > 0.f ? v : __expf(v) - 1.f; o.z = g.z * e + (1.f - g.z) * f4.z;
        v = c4.w * il + b4.w; e = v > 0.f ? v : __expf(v) - 1.f; o.w = g.w * e + (1.f - g.w) * f4.w;
        *(float4*)&out[base] = o;
    }
}

// ---------------------------------------------------------------------------
extern "C" void kernel_launch(void* const* d_in, const int* in_sizes, int n_in,
                              void* d_out, int out_size, void* d_ws, size_t ws_size,
                              hipStream_t stream) {
    const float* feat  = (const float*)d_in[0];
    const int*   adj   = (const int*)  d_in[1];
    const float* W     = (const float*)d_in[2];
    const float* bvec  = (const float*)d_in[3];
    const float* wsrc  = (const float*)d_in[4];
    const float* wdst  = (const float*)d_in[5];
    const float* Hw    = (const float*)d_in[6];
    const float* Hb    = (const float*)d_in[7];
    float* out = (float*)d_out;

    char* ws = (char*)d_ws;
    u16*    featb   = (u16*)(ws);                       // 6,291,456 B
    u16*    Wt      = (u16*)(ws + 6291456);             // 1,179,648 B
    u16*    Hwb     = (u16*)(ws + 7471104);             // 1,179,648 B
    u16*    hT      = (u16*)(ws + 8650752);             // 6,291,456 B
    float2* Spair   = (float2*)(ws + 14942208);         //   393,216 B
    float2* Dpair   = (float2*)(ws + 15335424);         //   393,216 B
    u32*    maskbuf = (u32*)(ws + 15728640);            //   262,144 B

    prep_kernel<<<PACK_BLOCKS + CONV_BLOCKS, 256, 0, stream>>>(
        adj, feat, W, Hw, maskbuf, featb, Wt, Hwb);
    gemm_h_kernel<<<dim3(MM / 64, AH), 256, 0, stream>>>(
        featb, Wt, wsrc, wdst, hT, Spair, Dpair);
    attn_kernel<<<dim3(NN / 64, YY), 256, 0, stream>>>(
        hT, Spair, Dpair, maskbuf, bvec, featb, Hwb, Hb, feat, out);
}

// Round 13
// 125.656 us; speedup vs baseline: 3.0892x; 1.0835x over previous
//
#include <hip/hip_runtime.h>
#include <hip/hip_bf16.h>

#define BB 8
#define NN 512
#define AH 12
#define DIN 768
#define EE 64
#define MM (BB*NN)          // 4096
#define YY (BB*AH)          // 96
#define LEAKY 0.2f

typedef unsigned short u16;
typedef unsigned int u32;
typedef __attribute__((ext_vector_type(8))) short short8;
typedef __attribute__((ext_vector_type(4))) float f32x4;
typedef __attribute__((ext_vector_type(4))) u32 u32x4;

// float -> bf16 RNE
static __device__ __forceinline__ u16 f2bf(float f) {
    u32 u = __builtin_bit_cast(u32, f);
    u32 r = (u + 0x7FFFu + ((u >> 16) & 1u)) >> 16;
    return (u16)r;
}
static __device__ __forceinline__ u32 pk2(float a, float b) {
    return (u32)f2bf(a) | ((u32)f2bf(b) << 16);
}
// truncation pack (p >= 0): used only for P (rel err <= 2^-8)
static __device__ __forceinline__ u32 pk2t(float a, float b) {
    return (__builtin_bit_cast(u32, a) >> 16) | (__builtin_bit_cast(u32, b) & 0xFFFF0000u);
}
static __device__ __forceinline__ float ftanh(float x) {
    x = fminf(fmaxf(x, -15.f), 15.f);
    return 1.f - 2.f / (__expf(2.f * x) + 1.f);
}
static __device__ __forceinline__ float sigm(float z) {
    z = fminf(fmaxf(z, -80.f), 80.f);
    return 1.f / (1.f + __expf(-z));
}
// async global->LDS, 16B per lane
static __device__ __forceinline__ void gl_lds16(const u16* g, u16* l) {
    __builtin_amdgcn_global_load_lds((const __attribute__((address_space(1))) unsigned int*)g,
                                     (__attribute__((address_space(3))) unsigned int*)l,
                                     16, 0, 0);
}

// ---------------------------------------------------------------------------
// Hardware C/D-layout probe (validated rounds 6-12).
// ---------------------------------------------------------------------------
static __device__ __forceinline__ void mfma_probe(int lane, int* prow, int* pcol) {
    int q = lane >> 4, x = lane & 15;
    short8 af, bf;
#pragma unroll
    for (int j = 0; j < 8; j++) {
        int k = q * 8 + j;
        af[j] = (short)f2bf((k < 16) ? (float)(x * 16 + k) : 0.f);
        bf[j] = (short)f2bf((k == x) ? 1.f : 0.f);
    }
    f32x4 d = {};
    d = __builtin_amdgcn_mfma_f32_16x16x32_bf16(af, bf, d, 0, 0, 0);
#pragma unroll
    for (int r = 0; r < 4; r++) {
        int v = (int)(d[r] + 0.5f);
        prow[r] = v >> 4;
        pcol[r] = v & 15;
    }
}

// ---------------------------------------------------------------------------
// Prep: pack_adj (blocks 0..1023) + bf16 conversions (verified).
// ---------------------------------------------------------------------------
#define N_FEAT (MM*DIN)            // 3145728
#define N_W    (AH*DIN*EE)         // 589824
#define PACK_BLOCKS (MM/4)         // 1024
#define CONV_BLOCKS ((N_FEAT + 2*N_W)/256)  // 16896
__global__ __launch_bounds__(256) void prep_kernel(const int* __restrict__ adj,
                                                   const float* __restrict__ feat,
                                                   const float* __restrict__ W,
                                                   const float* __restrict__ Hw,
                                                   u32* __restrict__ maskbuf,
                                                   u16* __restrict__ featb,
                                                   u16* __restrict__ Wt,
                                                   u16* __restrict__ Hwb) {
    int blk = blockIdx.x, t = threadIdx.x;
    if (blk < PACK_BLOCKS) {
        int w = t >> 6, ln = t & 63;
        int row = blk * 4 + w;
        const int* ar = adj + (size_t)row * NN;
#pragma unroll
        for (int it = 0; it < 8; it++) {
            unsigned long long bal = __ballot(ar[it * 64 + ln] != 0);
            if (ln == 0) {
                maskbuf[row * 16 + it * 2]     = (u32)bal;
                maskbuf[row * 16 + it * 2 + 1] = (u32)(bal >> 32);
            }
        }
        return;
    }
    int i = (blk - PACK_BLOCKS) * 256 + t;
    if (i < N_FEAT) { featb[i] = f2bf(feat[i]); return; }
    int i2 = i - N_FEAT;
    if (i2 < N_W) {
        int a = i2 / (DIN * EE), rem = i2 % (DIN * EE);
        int e = rem / DIN, d = rem % DIN;
        Wt[i2] = f2bf(W[a * (DIN * EE) + d * EE + e]);
        return;
    }
    int i3 = i2 - N_W;
    Hwb[i3] = f2bf(Hw[i3]);
}

// ---------------------------------------------------------------------------
// K-loop core (verified rounds 9-12): 64x64 C tile, BK=64, global_load_lds
// staging, XOR k-swizzle, probe-indexed C->LDS. Ends with __syncthreads.
// ---------------------------------------------------------------------------
#define GEMM_CORE(Abase, Bbase)                                               \
    int wm = w & 1, wn = w >> 1, xr = x & 7;                                  \
    int srow = t >> 3;                                                        \
    int skoff = ((t & 7) ^ (srow & 7)) * 8;                                   \
    const u16* Agp = (Abase) + srow * DIN + skoff;                            \
    const u16* Bgp = (Bbase) + srow * DIN + skoff;                            \
    u16* Asw = As + w * 512;                                                  \
    u16* Bsw = Bs + w * 512;                                                  \
    const u16* ApA = As + (wm * 32 + x) * 64;                                 \
    const u16* ApB = Bs + (wn * 32 + x) * 64;                                 \
    f32x4 acc00 = {}, acc01 = {}, acc10 = {}, acc11 = {};                     \
    for (int k0 = 0; k0 < DIN; k0 += 64) {                                    \
        gl_lds16(Agp + k0, Asw);                                              \
        gl_lds16(Agp + 32 * DIN + k0, Asw + 2048);                            \
        gl_lds16(Bgp + k0, Bsw);                                              \
        gl_lds16(Bgp + 32 * DIN + k0, Bsw + 2048);                            \
        __syncthreads();                                                      \
        _Pragma("unroll")                                                     \
        for (int kk = 0; kk < 2; kk++) {                                      \
            int c8 = ((q + kk * 4) ^ xr) * 8;                                 \
            short8 a0 = *(const short8*)(ApA + c8);                           \
            short8 a1 = *(const short8*)(ApA + 16 * 64 + c8);                 \
            short8 b0 = *(const short8*)(ApB + c8);                           \
            short8 b1 = *(const short8*)(ApB + 16 * 64 + c8);                 \
            acc00 = __builtin_amdgcn_mfma_f32_16x16x32_bf16(a0, b0, acc00, 0, 0, 0); \
            acc01 = __builtin_amdgcn_mfma_f32_16x16x32_bf16(a0, b1, acc01, 0, 0, 0); \
            acc10 = __builtin_amdgcn_mfma_f32_16x16x32_bf16(a1, b0, acc10, 0, 0, 0); \
            acc11 = __builtin_amdgcn_mfma_f32_16x16x32_bf16(a1, b1, acc11, 0, 0, 0); \
        }                                                                     \
        __syncthreads();                                                      \
    }                                                                         \
    int prow[4], pcol[4];                                                     \
    mfma_probe(lane, prow, pcol);                                             \
    _Pragma("unroll")                                                         \
    for (int r = 0; r < 4; r++) {                                             \
        cs[wm * 32 + prow[r]][wn * 32 + pcol[r]]           = acc00[r];        \
        cs[wm * 32 + prow[r]][wn * 32 + 16 + pcol[r]]      = acc01[r];        \
        cs[wm * 32 + 16 + prow[r]][wn * 32 + pcol[r]]      = acc10[r];        \
        cs[wm * 32 + 16 + prow[r]][wn * 32 + 16 + pcol[r]] = acc11[r];        \
    }                                                                         \
    __syncthreads();

// ---------------------------------------------------------------------------
// GEMM h: 64 nodes x 64 e (one head). Epilogue: bf16 hT3 [y][kc][e][8]
// (kc = node octet; PV-B-fragment-ready, 16B coalesced stores) + factored
// exp pairs (verified).
// ---------------------------------------------------------------------------
__global__ __launch_bounds__(256) void gemm_h_kernel(const u16* __restrict__ featb,
                                                     const u16* __restrict__ Wt,
                                                     const float* __restrict__ wsrc,
                                                     const float* __restrict__ wdst,
                                                     u16* __restrict__ hT,
                                                     float2* __restrict__ Spair,
                                                     float2* __restrict__ Dpair) {
    __shared__ u16 As[64 * 64];
    __shared__ u16 Bs[64 * 64];
    __shared__ alignas(16) float cs[64][68];
    int t = threadIdx.x, w = t >> 6, lane = t & 63, q = lane >> 4, x = lane & 15;
    int m0 = blockIdx.x * 64, a = blockIdx.y;

    GEMM_CORE(featb + (size_t)m0 * DIN, Wt + (size_t)a * EE * DIN)

    int b = m0 >> 9;
    int y = b * AH + a;
    int nbase = m0 & 511;
    // (a) hT3 [y][kc][e][8]: element (kc,e,j) = h[node kc*8+j][e]
    {
        int kcb = nbase >> 3;
#pragma unroll
        for (int i = 0; i < 2; i++) {
            int idx = i * 256 + t;
            int kcl = idx >> 6, e = idx & 63;
            int r0 = kcl * 8;
            u32x4 wv = { pk2(cs[r0 + 0][e], cs[r0 + 1][e]),
                         pk2(cs[r0 + 2][e], cs[r0 + 3][e]),
                         pk2(cs[r0 + 4][e], cs[r0 + 5][e]),
                         pk2(cs[r0 + 6][e], cs[r0 + 7][e]) };
            *(u32x4*)&hT[((((size_t)y << 6) + kcb + kcl) << 6 | e) * 8] = wv;
        }
    }
    // (b) factored exp pairs
    {
        int r = t >> 2, cg = t & 3;
        float s = 0.f, d = 0.f;
#pragma unroll
        for (int i = 0; i < 16; i++) {
            int e2 = cg * 16 + i;
            float th = ftanh(cs[r][e2]);
            s += th * wsrc[a * EE + e2];
            d += th * wdst[a * EE + e2];
        }
        s += __shfl_xor(s, 1); s += __shfl_xor(s, 2);
        d += __shfl_xor(d, 1); d += __shfl_xor(d, 2);
        if (cg == 0) {
            s = fminf(fmaxf(s, -40.f), 40.f);
            d = fminf(fmaxf(d, -40.f), 40.f);
            Spair[y * NN + nbase + r] = make_float2(__expf(s), __expf(0.2f * s));
            Dpair[y * NN + nbase + r] = make_float2(__expf(d), __expf(0.2f * d));
        }
    }
}

// ---------------------------------------------------------------------------
// Attention + fused gate GEMM (verified round 12) with coalesced hT3 B-loads.
// ---------------------------------------------------------------------------
__global__ __launch_bounds__(256) void attn_kernel(const u16* __restrict__ hT,
                                                   const float2* __restrict__ Spair,
                                                   const float2* __restrict__ Dpair,
                                                   const u32* __restrict__ maskbuf,
                                                   const float* __restrict__ bias,
                                                   const u16* __restrict__ featb,
                                                   const u16* __restrict__ Hwb,
                                                   const float* __restrict__ Hb,
                                                   const float* __restrict__ feat,
                                                   float* __restrict__ out) {
    __shared__ union {
        u16 stage[2][64 * 64];                       // As/Bs during gate GEMM
        struct {
            float2 sd2[NN];                          // 4 KB
            u32 smask[64][17];                       // 4.35 KB
        } pv;
    } ushr;
    __shared__ alignas(16) float cs[64][68];
    __shared__ float silv[64];

    int t = threadIdx.x;
    int y = blockIdx.y, bb = y / AH, a = y % AH;
    int i0 = blockIdx.x * 64;
    int w = t >> 6, lane = t & 63, q = lane >> 4, x = lane & 15;

    // ---- phase 1: gate GEMM tile -> sigmoid in registers ----
    float4 g4[4];
    {
        u16* As = ushr.stage[0];
        u16* Bs = ushr.stage[1];
        GEMM_CORE(featb + ((size_t)(bb << 9) + i0) * DIN, Hwb + (size_t)(a * EE) * DIN)
        float4 hb = *(const float4*)&Hb[a * EE + (t & 15) * 4];
#pragma unroll
        for (int p = 0; p < 4; p++) {
            int ml = p * 16 + (t >> 4), c4 = (t & 15) * 4;
            float4 v4 = *(const float4*)&cs[ml][c4];
            g4[p].x = sigm(v4.x + hb.x);
            g4[p].y = sigm(v4.y + hb.y);
            g4[p].z = sigm(v4.z + hb.z);
            g4[p].w = sigm(v4.w + hb.w);
        }
    }

    // ---- load PV working set (staging region is dead; union reuse) ----
    float2* sd2 = ushr.pv.sd2;
    u32 (*smask)[17] = ushr.pv.smask;
    sd2[t] = Dpair[y * NN + t];
    sd2[t + 256] = Dpair[y * NN + 256 + t];
#pragma unroll
    for (int p = 0; p < 4; p++) {
        int idx = p * 256 + t, r = idx >> 4, c = idx & 15;
        smask[r][c] = maskbuf[((bb << 9) + i0 + r) * 16 + c];
    }
    __syncthreads();

    // ---- phase 2: PV via MFMA (factored exp, on-the-fly row sum) ----
    int rowl = w * 16 + x;
    float2 se = Spair[y * NN + i0 + rowl];
    float es1 = se.x, es2 = se.y;

    u32 anym = 0;
#pragma unroll
    for (int c = 0; c < 16; c++) anym |= smask[rowl][c];
    int uni = (anym == 0);

    const u16* hTy = hT + ((size_t)y << 12) * 8;     // y * 64 * 64 * 8
    f32x4 acc[4] = {};
    float lsum = 0.f;

#pragma unroll 2
    for (int k0 = 0; k0 < NN; k0 += 32) {
        u32 mb = smask[rowl][k0 >> 5] >> (q * 8);
        float pv[8];
#pragma unroll
        for (int j = 0; j < 8; j++) {
            float2 dp = sd2[k0 + q * 8 + j];
            float m1 = es1 * dp.x;
            float m2 = es2 * dp.y;
            float p = (m1 >= 1.f) ? m1 : m2;    // exp(leaky(s+d))
            p = ((mb >> j) & 1) ? p : 0.f;
            p = uni ? 1.0f : p;
            lsum += p;
            pv[j] = p;
        }
        short8 af = __builtin_bit_cast(short8, (u32x4){
            pk2t(pv[0], pv[1]), pk2t(pv[2], pv[3]),
            pk2t(pv[4], pv[5]), pk2t(pv[6], pv[7])});
        // hT3 [kc][e][8]: lane (q,x) chunk kc=(k0>>3)+q, e = e_off + x
        const u16* hp = hTy + ((((k0 >> 3) + q) << 6) + x) * 8;
        short8 b0 = *(const short8*)(hp);
        short8 b1 = *(const short8*)(hp + 16 * 8);
        short8 b2 = *(const short8*)(hp + 32 * 8);
        short8 b3 = *(const short8*)(hp + 48 * 8);
        acc[0] = __builtin_amdgcn_mfma_f32_16x16x32_bf16(af, b0, acc[0], 0, 0, 0);
        acc[1] = __builtin_amdgcn_mfma_f32_16x16x32_bf16(af, b1, acc[1], 0, 0, 0);
        acc[2] = __builtin_amdgcn_mfma_f32_16x16x32_bf16(af, b2, acc[2], 0, 0, 0);
        acc[3] = __builtin_amdgcn_mfma_f32_16x16x32_bf16(af, b3, acc[3], 0, 0, 0);
    }

    lsum += __shfl_xor(lsum, 16);
    lsum += __shfl_xor(lsum, 32);
    if (q == 0) silv[rowl] = 1.f / fmaxf(lsum, 1e-30f);

    int prow[4], pcol[4];
    mfma_probe(lane, prow, pcol);
#pragma unroll
    for (int nt = 0; nt < 4; nt++)
#pragma unroll
        for (int r = 0; r < 4; r++)
            cs[w * 16 + prow[r]][nt * 16 + pcol[r]] = acc[nt][r];
    __syncthreads();

    // ---- epilogue: normalize, +bias, elu, gate blend ----
    float4 b4 = *(const float4*)&bias[(t & 15) * 4];
#pragma unroll
    for (int p = 0; p < 4; p++) {
        int nl = p * 16 + (t >> 4), e4 = (t & 15) * 4;
        float il = silv[nl];
        float4 c4 = *(const float4*)&cs[nl][e4];
        size_t base = ((size_t)(bb << 9) + i0 + nl) * DIN + a * EE + e4;
        float4 f4 = *(const float4*)&feat[base];
        float4 g = g4[p];
        float4 o;
        float v, e;
        v = c4.x * il + b4.x; e = v > 0.f ? v : __expf(v) - 1.f; o.x = g.x * e + (1.f - g.x) * f4.x;
        v = c4.y * il + b4.y; e = v > 0.f ? v : __expf(v) - 1.f; o.y = g.y * e + (1.f - g.y) * f4.y;
        v = c4.z * il + b4.z; e = v > 0.f ? v : __expf(v) - 1.f; o.z = g.z * e + (1.f - g.z) * f4.z;
        v = c4.w * il + b4.w; e = v > 0.f ? v : __expf(v) - 1.f; o.w = g.w * e + (1.f - g.w) * f4.w;
        *(float4*)&out[base] = o;
    }
}

// ---------------------------------------------------------------------------
extern "C" void kernel_launch(void* const* d_in, const int* in_sizes, int n_in,
                              void* d_out, int out_size, void* d_ws, size_t ws_size,
                              hipStream_t stream) {
    const float* feat  = (const float*)d_in[0];
    const int*   adj   = (const int*)  d_in[1];
    const float* W     = (const float*)d_in[2];
    const float* bvec  = (const float*)d_in[3];
    const float* wsrc  = (const float*)d_in[4];
    const float* wdst  = (const float*)d_in[5];
    const float* Hw    = (const float*)d_in[6];
    const float* Hb    = (const float*)d_in[7];
    float* out = (float*)d_out;

    char* ws = (char*)d_ws;
    u16*    featb   = (u16*)(ws);                       // 6,291,456 B
    u16*    Wt      = (u16*)(ws + 6291456);             // 1,179,648 B
    u16*    Hwb     = (u16*)(ws + 7471104);             // 1,179,648 B
    u16*    hT      = (u16*)(ws + 8650752);             // 6,291,456 B
    float2* Spair   = (float2*)(ws + 14942208);         //   393,216 B
    float2* Dpair   = (float2*)(ws + 15335424);         //   393,216 B
    u32*    maskbuf = (u32*)(ws + 15728640);            //   262,144 B

    prep_kernel<<<PACK_BLOCKS + CONV_BLOCKS, 256, 0, stream>>>(
        adj, feat, W, Hw, maskbuf, featb, Wt, Hwb);
    gemm_h_kernel<<<dim3(MM / 64, AH), 256, 0, stream>>>(
        featb, Wt, wsrc, wdst, hT, Spair, Dpair);
    attn_kernel<<<dim3(NN / 64, YY), 256, 0, stream>>>(
        hT, Spair, Dpair, maskbuf, bvec, featb, Hwb, Hb, feat, out);
}